// Round 1
// baseline (8812.795 us; speedup 1.0000x reference)
//
#include <hip/hip_runtime.h>
#include <hip/hip_bf16.h>

#define V_NODES 100000
#define E_EDGES 600000
#define D_FEAT  128
#define VD      ((size_t)V_NODES * D_FEAT)

// ---------------------------------------------------------------------------
// Weight pre-transpose: wt[m][k*128+j] = W[m][j*128+k]   (m = 2*layer + sel)
// ---------------------------------------------------------------------------
__global__ void transpose_w_kernel(const float* __restrict__ W0,
                                   const float* __restrict__ W1,
                                   float* __restrict__ wt) {
    int m = blockIdx.y;            // 0..7
    int l = m >> 1, s = m & 1;
    const float* W = (s ? W1 : W0) + (size_t)l * 16384;
    float* T = wt + (size_t)m * 16384;
    int i = blockIdx.x * 256 + threadIdx.x;   // 0..16383
    int k = i >> 7, j = i & 127;
    T[k * 128 + j] = W[j * 128 + k];
}

// ---------------------------------------------------------------------------
// Dual GEMM: out[i][j] = sum_k x[i][k] * W[j][k] + bias[j]
// blockIdx.y = 0 -> (wt0,b0,out0), 1 -> (wt1,b1,out1)
// 64 rows per block, full 128 cols, K=128 fully in LDS.
// ---------------------------------------------------------------------------
__global__ __launch_bounds__(256) void gemm_dual_kernel(
    const float* __restrict__ x,
    const float* __restrict__ wt0, const float* __restrict__ bias0, float* __restrict__ out0,
    const float* __restrict__ wt1, const float* __restrict__ bias1, float* __restrict__ out1,
    int V) {
    const float* wt   = (blockIdx.y == 0) ? wt0   : wt1;
    const float* bias = (blockIdx.y == 0) ? bias0 : bias1;
    float*       out  = (blockIdx.y == 0) ? out0  : out1;

    __shared__ float xs[64 * 132];           // xs[r][k], stride 132 (16B aligned)
    const int t  = threadIdx.x;
    const int m0 = blockIdx.x * 64;

    // Stage 64 rows x 128 cols of x into LDS (coalesced float4 reads).
#pragma unroll
    for (int it = 0; it < 8; ++it) {
        int i  = it * 256 + t;               // 0..2047 float4 slots
        int c4 = i & 31;                     // float4 col chunk
        int r  = i >> 5;                     // row 0..63
        float4 v = make_float4(0.f, 0.f, 0.f, 0.f);
        int row = m0 + r;
        if (row < V)
            v = reinterpret_cast<const float4*>(x + (size_t)row * 128)[c4];
        *reinterpret_cast<float4*>(&xs[r * 132 + c4 * 4]) = v;
    }
    __syncthreads();

    const int cg = t & 15;                   // col group: cols 8*cg..8*cg+7
    const int rg = t >> 4;                   // row group: rows 4*rg..4*rg+3

    float acc[4][8];
#pragma unroll
    for (int i = 0; i < 4; ++i)
#pragma unroll
        for (int j = 0; j < 8; ++j) acc[i][j] = 0.f;

    for (int k4 = 0; k4 < 32; ++k4) {
        alignas(16) float a[4][4];           // [row][kk]
#pragma unroll
        for (int i = 0; i < 4; ++i)
            *reinterpret_cast<float4*>(a[i]) =
                *reinterpret_cast<const float4*>(&xs[(rg * 4 + i) * 132 + k4 * 4]);
#pragma unroll
        for (int kk = 0; kk < 4; ++kk) {
            alignas(16) float bv[8];
            *reinterpret_cast<float4*>(bv) =
                *reinterpret_cast<const float4*>(&wt[(k4 * 4 + kk) * 128 + cg * 8]);
            *reinterpret_cast<float4*>(bv + 4) =
                *reinterpret_cast<const float4*>(&wt[(k4 * 4 + kk) * 128 + cg * 8 + 4]);
#pragma unroll
            for (int i = 0; i < 4; ++i)
#pragma unroll
                for (int j = 0; j < 8; ++j)
                    acc[i][j] += a[i][kk] * bv[j];
        }
    }

    alignas(16) float bvv[8];
    *reinterpret_cast<float4*>(bvv)     = *reinterpret_cast<const float4*>(&bias[cg * 8]);
    *reinterpret_cast<float4*>(bvv + 4) = *reinterpret_cast<const float4*>(&bias[cg * 8 + 4]);

#pragma unroll
    for (int i = 0; i < 4; ++i) {
        int row = m0 + rg * 4 + i;
        if (row < V) {
            alignas(16) float o[8];
#pragma unroll
            for (int j = 0; j < 8; ++j) o[j] = acc[i][j] + bvv[j];
            *reinterpret_cast<float4*>(&out[(size_t)row * 128 + cg * 8]) =
                *reinterpret_cast<const float4*>(o);
            *reinterpret_cast<float4*>(&out[(size_t)row * 128 + cg * 8 + 4]) =
                *reinterpret_cast<const float4*>(o + 4);
        }
    }
}

// ---------------------------------------------------------------------------
// Edge scatter: out[a] += y[b]; out[b] += y[a]  for each edge (a,b).
// 32 lanes per edge, float4 per lane, scalar atomics.
// ---------------------------------------------------------------------------
__global__ __launch_bounds__(256) void scatter_kernel(
    const float* __restrict__ y, const int* __restrict__ edges,
    float* __restrict__ out, int E) {
    int g    = (blockIdx.x * 256 + threadIdx.x) >> 5;   // edge index
    int lane = threadIdx.x & 31;
    if (g >= E) return;
    int a = edges[2 * g], b = edges[2 * g + 1];
    const float4 va = *reinterpret_cast<const float4*>(&y[(size_t)a * 128 + lane * 4]);
    const float4 vb = *reinterpret_cast<const float4*>(&y[(size_t)b * 128 + lane * 4]);
    float* oa = &out[(size_t)a * 128 + lane * 4];
    float* ob = &out[(size_t)b * 128 + lane * 4];
    atomicAdd(ob + 0, va.x); atomicAdd(ob + 1, va.y);
    atomicAdd(ob + 2, va.z); atomicAdd(ob + 3, va.w);
    atomicAdd(oa + 0, vb.x); atomicAdd(oa + 1, vb.y);
    atomicAdd(oa + 2, vb.z); atomicAdd(oa + 3, vb.w);
}

// ---------------------------------------------------------------------------
// Zero a small float buffer (stats)
// ---------------------------------------------------------------------------
__global__ void zero_kernel(float* __restrict__ p, int n) {
    int i = blockIdx.x * 256 + threadIdx.x;
    if (i < n) p[i] = 0.f;
}

// ---------------------------------------------------------------------------
// BN stats: stats[0..127] = col sums, stats[128..255] = col sums of squares
// ---------------------------------------------------------------------------
__global__ __launch_bounds__(256) void bn_stats_kernel(
    const float* __restrict__ x, float* __restrict__ stats, int V, int rows_pb) {
    const int t    = threadIdx.x;
    const int col  = t & 127;
    const int half = t >> 7;
    int r0 = blockIdx.x * rows_pb;
    int r1 = min(V, r0 + rows_pb);
    float s = 0.f, ss = 0.f;
    for (int r = r0 + half; r < r1; r += 2) {
        float v = x[(size_t)r * 128 + col];
        s += v;
        ss += v * v;
    }
    __shared__ float sh[256];
    sh[t] = s;
    __syncthreads();
    if (t < 128) atomicAdd(&stats[t], sh[t] + sh[t + 128]);
    __syncthreads();
    sh[t] = ss;
    __syncthreads();
    if (t < 128) atomicAdd(&stats[128 + t], sh[t] + sh[t + 128]);
}

// ---------------------------------------------------------------------------
// Normalize + optional residual + ReLU:  out = relu(gamma*(x-mu)*rsqrt(var+eps)+beta [+res])
// ---------------------------------------------------------------------------
__global__ __launch_bounds__(256) void bn_norm_relu_kernel(
    const float* __restrict__ x, const float* __restrict__ stats,
    const float* __restrict__ gamma, const float* __restrict__ beta,
    const float* __restrict__ res, float* __restrict__ outp, int V) {
    size_t idx = (size_t)blockIdx.x * 256 + threadIdx.x;   // float4 index
    size_t n4  = (size_t)V * 32;
    if (idx >= n4) return;
    int c4  = (int)(idx & 31);
    int col = c4 * 4;
    const float inv = 1.0f / (float)V;
    float4 v   = reinterpret_cast<const float4*>(x)[idx];
    float4 sum = *reinterpret_cast<const float4*>(&stats[col]);
    float4 ssq = *reinterpret_cast<const float4*>(&stats[128 + col]);
    float4 g   = *reinterpret_cast<const float4*>(&gamma[col]);
    float4 bb  = *reinterpret_cast<const float4*>(&beta[col]);

    float4 o;
    {
        float mu = sum.x * inv; float var = ssq.x * inv - mu * mu;
        float sc = g.x * rsqrtf(var + 1e-5f); o.x = v.x * sc + (bb.x - mu * sc);
    }
    {
        float mu = sum.y * inv; float var = ssq.y * inv - mu * mu;
        float sc = g.y * rsqrtf(var + 1e-5f); o.y = v.y * sc + (bb.y - mu * sc);
    }
    {
        float mu = sum.z * inv; float var = ssq.z * inv - mu * mu;
        float sc = g.z * rsqrtf(var + 1e-5f); o.z = v.z * sc + (bb.z - mu * sc);
    }
    {
        float mu = sum.w * inv; float var = ssq.w * inv - mu * mu;
        float sc = g.w * rsqrtf(var + 1e-5f); o.w = v.w * sc + (bb.w - mu * sc);
    }
    if (res) {
        float4 rv = reinterpret_cast<const float4*>(res)[idx];
        o.x += rv.x; o.y += rv.y; o.z += rv.z; o.w += rv.w;
    }
    o.x = fmaxf(o.x, 0.f); o.y = fmaxf(o.y, 0.f);
    o.z = fmaxf(o.z, 0.f); o.w = fmaxf(o.w, 0.f);
    reinterpret_cast<float4*>(outp)[idx] = o;
}

// ---------------------------------------------------------------------------
extern "C" void kernel_launch(void* const* d_in, const int* in_sizes, int n_in,
                              void* d_out, int out_size, void* d_ws, size_t ws_size,
                              hipStream_t stream) {
    const float* feat  = (const float*)d_in[0];
    const int*   edges = (const int*)d_in[1];
    const float* W0    = (const float*)d_in[2];
    const float* b0    = (const float*)d_in[3];
    const float* W1    = (const float*)d_in[4];
    const float* b1    = (const float*)d_in[5];
    const float* gamma = (const float*)d_in[6];
    const float* beta  = (const float*)d_in[7];
    float* out = (float*)d_out;

    float* buf_f = (float*)d_ws;           // [V,128] normalized activations
    float* buf_y = buf_f + VD;             // [V,128] neighbor-message features
    float* wt    = buf_y + VD;             // 8 x 128 x 128 transposed weights
    float* stats = wt + 8 * 16384;         // 256 floats

    const int V = V_NODES, E = E_EDGES;
    const int gemm_blocks = (V + 63) / 64;             // 1563
    const int scat_blocks = (E * 32 + 255) / 256;      // 75000
    const int norm_blocks = (int)(((size_t)V * 32 + 255) / 256);
    const int stat_grid   = 256;
    const int rows_pb     = (V + stat_grid - 1) / stat_grid;

    transpose_w_kernel<<<dim3(64, 8), 256, 0, stream>>>(W0, W1, wt);

    const float* x = feat;
    for (int l = 0; l < 4; ++l) {
        gemm_dual_kernel<<<dim3(gemm_blocks, 2), 256, 0, stream>>>(
            x,
            wt + (size_t)(2 * l) * 16384,     b0 + l * 128, out,
            wt + (size_t)(2 * l + 1) * 16384, b1 + l * 128, buf_y,
            V);
        scatter_kernel<<<scat_blocks, 256, 0, stream>>>(buf_y, edges, out, E);
        if (l < 3) {
            zero_kernel<<<1, 256, 0, stream>>>(stats, 256);
            bn_stats_kernel<<<stat_grid, 256, 0, stream>>>(out, stats, V, rows_pb);
            bn_norm_relu_kernel<<<norm_blocks, 256, 0, stream>>>(
                out, stats, gamma + l * 128, beta + l * 128,
                (l == 2) ? feat : nullptr, buf_f, V);
            x = buf_f;
        }
    }
}

// Round 2
// 1436.398 us; speedup vs baseline: 6.1353x; 6.1353x over previous
//
#include <hip/hip_runtime.h>
#include <hip/hip_bf16.h>

#define V_NODES 100000
#define E_EDGES 600000
#define D_FEAT  128
#define VD      ((size_t)V_NODES * D_FEAT)

// ---------------------------------------------------------------------------
// Weight pre-transpose: wt[m][k*128+j] = W[m][j*128+k]   (m = 2*layer + sel)
// ---------------------------------------------------------------------------
__global__ void transpose_w_kernel(const float* __restrict__ W0,
                                   const float* __restrict__ W1,
                                   float* __restrict__ wt) {
    int m = blockIdx.y;            // 0..7
    int l = m >> 1, s = m & 1;
    const float* W = (s ? W1 : W0) + (size_t)l * 16384;
    float* T = wt + (size_t)m * 16384;
    int i = blockIdx.x * 256 + threadIdx.x;   // 0..16383
    int k = i >> 7, j = i & 127;
    T[k * 128 + j] = W[j * 128 + k];
}

// ---------------------------------------------------------------------------
// Dual GEMM: out[i][j] = sum_k x[i][k] * W[j][k] + bias[j]
// ---------------------------------------------------------------------------
__global__ __launch_bounds__(256) void gemm_dual_kernel(
    const float* __restrict__ x,
    const float* __restrict__ wt0, const float* __restrict__ bias0, float* __restrict__ out0,
    const float* __restrict__ wt1, const float* __restrict__ bias1, float* __restrict__ out1,
    int V) {
    const float* wt   = (blockIdx.y == 0) ? wt0   : wt1;
    const float* bias = (blockIdx.y == 0) ? bias0 : bias1;
    float*       out  = (blockIdx.y == 0) ? out0  : out1;

    __shared__ float xs[64 * 132];           // xs[r][k], stride 132 (16B aligned)
    const int t  = threadIdx.x;
    const int m0 = blockIdx.x * 64;

#pragma unroll
    for (int it = 0; it < 8; ++it) {
        int i  = it * 256 + t;               // 0..2047 float4 slots
        int c4 = i & 31;
        int r  = i >> 5;
        float4 v = make_float4(0.f, 0.f, 0.f, 0.f);
        int row = m0 + r;
        if (row < V)
            v = reinterpret_cast<const float4*>(x + (size_t)row * 128)[c4];
        *reinterpret_cast<float4*>(&xs[r * 132 + c4 * 4]) = v;
    }
    __syncthreads();

    const int cg = t & 15;                   // cols 8*cg..8*cg+7
    const int rg = t >> 4;                   // rows 4*rg..4*rg+3

    float acc[4][8];
#pragma unroll
    for (int i = 0; i < 4; ++i)
#pragma unroll
        for (int j = 0; j < 8; ++j) acc[i][j] = 0.f;

    for (int k4 = 0; k4 < 32; ++k4) {
        alignas(16) float a[4][4];
#pragma unroll
        for (int i = 0; i < 4; ++i)
            *reinterpret_cast<float4*>(a[i]) =
                *reinterpret_cast<const float4*>(&xs[(rg * 4 + i) * 132 + k4 * 4]);
#pragma unroll
        for (int kk = 0; kk < 4; ++kk) {
            alignas(16) float bv[8];
            *reinterpret_cast<float4*>(bv) =
                *reinterpret_cast<const float4*>(&wt[(k4 * 4 + kk) * 128 + cg * 8]);
            *reinterpret_cast<float4*>(bv + 4) =
                *reinterpret_cast<const float4*>(&wt[(k4 * 4 + kk) * 128 + cg * 8 + 4]);
#pragma unroll
            for (int i = 0; i < 4; ++i)
#pragma unroll
                for (int j = 0; j < 8; ++j)
                    acc[i][j] += a[i][kk] * bv[j];
        }
    }

    alignas(16) float bvv[8];
    *reinterpret_cast<float4*>(bvv)     = *reinterpret_cast<const float4*>(&bias[cg * 8]);
    *reinterpret_cast<float4*>(bvv + 4) = *reinterpret_cast<const float4*>(&bias[cg * 8 + 4]);

#pragma unroll
    for (int i = 0; i < 4; ++i) {
        int row = m0 + rg * 4 + i;
        if (row < V) {
            alignas(16) float o[8];
#pragma unroll
            for (int j = 0; j < 8; ++j) o[j] = acc[i][j] + bvv[j];
            *reinterpret_cast<float4*>(&out[(size_t)row * 128 + cg * 8]) =
                *reinterpret_cast<const float4*>(o);
            *reinterpret_cast<float4*>(&out[(size_t)row * 128 + cg * 8 + 4]) =
                *reinterpret_cast<const float4*>(o + 4);
        }
    }
}

// ---------------------------------------------------------------------------
// CSR construction (edges are constant across layers; rebuilt every launch)
// ---------------------------------------------------------------------------
__global__ void zero_int_kernel(int* __restrict__ p, int n) {
    int i = blockIdx.x * 256 + threadIdx.x;
    if (i < n) p[i] = 0;
}

__global__ __launch_bounds__(256) void degree_kernel(
    const int* __restrict__ edges, int* __restrict__ deg, int E) {
    int i = blockIdx.x * 256 + threadIdx.x;
    if (i >= E) return;
    atomicAdd(&deg[edges[2 * i]], 1);
    atomicAdd(&deg[edges[2 * i + 1]], 1);
}

__global__ __launch_bounds__(1024) void scan_kernel(
    const int* __restrict__ deg, int* __restrict__ offsets, int V) {
    __shared__ int sh[1024];
    const int t = threadIdx.x;
    const int chunk = (V + 1023) / 1024;
    int s0 = t * chunk, s1 = min(V, s0 + chunk);
    int sum = 0;
    for (int i = s0; i < s1; ++i) sum += deg[i];
    sh[t] = sum;
    __syncthreads();
    for (int off = 1; off < 1024; off <<= 1) {
        int add = (t >= off) ? sh[t - off] : 0;
        __syncthreads();
        sh[t] += add;
        __syncthreads();
    }
    int run = (t == 0) ? 0 : sh[t - 1];
    for (int i = s0; i < s1; ++i) { offsets[i] = run; run += deg[i]; }
    if (t == 1023) offsets[V] = run;
}

__global__ void copy_int_kernel(const int* __restrict__ a, int* __restrict__ b, int n) {
    int i = blockIdx.x * 256 + threadIdx.x;
    if (i < n) b[i] = a[i];
}

__global__ __launch_bounds__(256) void fill_adj_kernel(
    const int* __restrict__ edges, int* __restrict__ cursor,
    int* __restrict__ adj, int E) {
    int i = blockIdx.x * 256 + threadIdx.x;
    if (i >= E) return;
    int a = edges[2 * i], b = edges[2 * i + 1];
    int pa = atomicAdd(&cursor[a], 1);
    adj[pa] = b;
    int pb = atomicAdd(&cursor[b], 1);
    adj[pb] = a;
}

// ---------------------------------------------------------------------------
// Gather: out[v] += sum over neighbors u of y[u].   32 lanes (float4) / node.
// ---------------------------------------------------------------------------
__global__ __launch_bounds__(256) void gather_kernel(
    const float* __restrict__ y, const int* __restrict__ offsets,
    const int* __restrict__ adj, float* __restrict__ out, int V) {
    const int t    = threadIdx.x;
    const int node = blockIdx.x * 8 + (t >> 5);
    if (node >= V) return;
    const int c4 = t & 31;
    int start = offsets[node], end = offsets[node + 1];

    float4 acc0 = make_float4(0.f, 0.f, 0.f, 0.f);
    float4 acc1 = make_float4(0.f, 0.f, 0.f, 0.f);
    int i = start;
    for (; i + 1 < end; i += 2) {
        int u0 = adj[i], u1 = adj[i + 1];
        float4 v0 = *reinterpret_cast<const float4*>(&y[(size_t)u0 * 128 + c4 * 4]);
        float4 v1 = *reinterpret_cast<const float4*>(&y[(size_t)u1 * 128 + c4 * 4]);
        acc0.x += v0.x; acc0.y += v0.y; acc0.z += v0.z; acc0.w += v0.w;
        acc1.x += v1.x; acc1.y += v1.y; acc1.z += v1.z; acc1.w += v1.w;
    }
    if (i < end) {
        int u0 = adj[i];
        float4 v0 = *reinterpret_cast<const float4*>(&y[(size_t)u0 * 128 + c4 * 4]);
        acc0.x += v0.x; acc0.y += v0.y; acc0.z += v0.z; acc0.w += v0.w;
    }
    float* op = &out[(size_t)node * 128 + c4 * 4];
    float4 o = *reinterpret_cast<const float4*>(op);
    o.x += acc0.x + acc1.x; o.y += acc0.y + acc1.y;
    o.z += acc0.z + acc1.z; o.w += acc0.w + acc1.w;
    *reinterpret_cast<float4*>(op) = o;
}

// ---------------------------------------------------------------------------
// BN
// ---------------------------------------------------------------------------
__global__ void zero_kernel(float* __restrict__ p, int n) {
    int i = blockIdx.x * 256 + threadIdx.x;
    if (i < n) p[i] = 0.f;
}

__global__ __launch_bounds__(256) void bn_stats_kernel(
    const float* __restrict__ x, float* __restrict__ stats, int V, int rows_pb) {
    const int t    = threadIdx.x;
    const int col  = t & 127;
    const int half = t >> 7;
    int r0 = blockIdx.x * rows_pb;
    int r1 = min(V, r0 + rows_pb);
    float s = 0.f, ss = 0.f;
    for (int r = r0 + half; r < r1; r += 2) {
        float v = x[(size_t)r * 128 + col];
        s += v;
        ss += v * v;
    }
    __shared__ float sh[256];
    sh[t] = s;
    __syncthreads();
    if (t < 128) atomicAdd(&stats[t], sh[t] + sh[t + 128]);
    __syncthreads();
    sh[t] = ss;
    __syncthreads();
    if (t < 128) atomicAdd(&stats[128 + t], sh[t] + sh[t + 128]);
}

__global__ __launch_bounds__(256) void bn_norm_relu_kernel(
    const float* __restrict__ x, const float* __restrict__ stats,
    const float* __restrict__ gamma, const float* __restrict__ beta,
    const float* __restrict__ res, float* __restrict__ outp, int V) {
    size_t idx = (size_t)blockIdx.x * 256 + threadIdx.x;   // float4 index
    size_t n4  = (size_t)V * 32;
    if (idx >= n4) return;
    int c4  = (int)(idx & 31);
    int col = c4 * 4;
    const float inv = 1.0f / (float)V;
    float4 v   = reinterpret_cast<const float4*>(x)[idx];
    float4 sum = *reinterpret_cast<const float4*>(&stats[col]);
    float4 ssq = *reinterpret_cast<const float4*>(&stats[128 + col]);
    float4 g   = *reinterpret_cast<const float4*>(&gamma[col]);
    float4 bb  = *reinterpret_cast<const float4*>(&beta[col]);

    float4 o;
    {
        float mu = sum.x * inv; float var = ssq.x * inv - mu * mu;
        float sc = g.x * rsqrtf(var + 1e-5f); o.x = v.x * sc + (bb.x - mu * sc);
    }
    {
        float mu = sum.y * inv; float var = ssq.y * inv - mu * mu;
        float sc = g.y * rsqrtf(var + 1e-5f); o.y = v.y * sc + (bb.y - mu * sc);
    }
    {
        float mu = sum.z * inv; float var = ssq.z * inv - mu * mu;
        float sc = g.z * rsqrtf(var + 1e-5f); o.z = v.z * sc + (bb.z - mu * sc);
    }
    {
        float mu = sum.w * inv; float var = ssq.w * inv - mu * mu;
        float sc = g.w * rsqrtf(var + 1e-5f); o.w = v.w * sc + (bb.w - mu * sc);
    }
    if (res) {
        float4 rv = reinterpret_cast<const float4*>(res)[idx];
        o.x += rv.x; o.y += rv.y; o.z += rv.z; o.w += rv.w;
    }
    o.x = fmaxf(o.x, 0.f); o.y = fmaxf(o.y, 0.f);
    o.z = fmaxf(o.z, 0.f); o.w = fmaxf(o.w, 0.f);
    reinterpret_cast<float4*>(outp)[idx] = o;
}

// ---------------------------------------------------------------------------
extern "C" void kernel_launch(void* const* d_in, const int* in_sizes, int n_in,
                              void* d_out, int out_size, void* d_ws, size_t ws_size,
                              hipStream_t stream) {
    const float* feat  = (const float*)d_in[0];
    const int*   edges = (const int*)d_in[1];
    const float* W0    = (const float*)d_in[2];
    const float* b0    = (const float*)d_in[3];
    const float* W1    = (const float*)d_in[4];
    const float* b1    = (const float*)d_in[5];
    const float* gamma = (const float*)d_in[6];
    const float* beta  = (const float*)d_in[7];
    float* out = (float*)d_out;

    float* buf_f = (float*)d_ws;           // [V,128] normalized activations
    float* buf_y = buf_f + VD;             // [V,128] neighbor-message features
    float* wt    = buf_y + VD;             // 8 x 128 x 128 transposed weights
    float* stats = wt + 8 * 16384;         // 256 floats
    int*   deg     = (int*)(stats + 256);  // V
    int*   offsets = deg + V_NODES;        // V+1
    int*   cursor  = offsets + V_NODES + 1;// V
    int*   adj     = cursor + V_NODES;     // 2E

    const int V = V_NODES, E = E_EDGES;
    const int gemm_blocks = (V + 63) / 64;
    const int gath_blocks = (V + 7) / 8;
    const int norm_blocks = (int)(((size_t)V * 32 + 255) / 256);
    const int stat_grid   = 256;
    const int rows_pb     = (V + stat_grid - 1) / stat_grid;
    const int vblocks     = (V + 255) / 256;
    const int eblocks     = (E + 255) / 256;

    // One-time (per launch) prep: weight transpose + CSR build
    transpose_w_kernel<<<dim3(64, 8), 256, 0, stream>>>(W0, W1, wt);
    zero_int_kernel<<<vblocks, 256, 0, stream>>>(deg, V);
    degree_kernel<<<eblocks, 256, 0, stream>>>(edges, deg, E);
    scan_kernel<<<1, 1024, 0, stream>>>(deg, offsets, V);
    copy_int_kernel<<<vblocks, 256, 0, stream>>>(offsets, cursor, V);
    fill_adj_kernel<<<eblocks, 256, 0, stream>>>(edges, cursor, adj, E);

    const float* x = feat;
    for (int l = 0; l < 4; ++l) {
        gemm_dual_kernel<<<dim3(gemm_blocks, 2), 256, 0, stream>>>(
            x,
            wt + (size_t)(2 * l) * 16384,     b0 + l * 128, out,
            wt + (size_t)(2 * l + 1) * 16384, b1 + l * 128, buf_y,
            V);
        gather_kernel<<<gath_blocks, 256, 0, stream>>>(buf_y, offsets, adj, out, V);
        if (l < 3) {
            zero_kernel<<<1, 256, 0, stream>>>(stats, 256);
            bn_stats_kernel<<<stat_grid, 256, 0, stream>>>(out, stats, V, rows_pb);
            bn_norm_relu_kernel<<<norm_blocks, 256, 0, stream>>>(
                out, stats, gamma + l * 128, beta + l * 128,
                (l == 2) ? feat : nullptr, buf_f, V);
            x = buf_f;
        }
    }
}

// Round 3
// 1238.885 us; speedup vs baseline: 7.1135x; 1.1594x over previous
//
#include <hip/hip_runtime.h>
#include <hip/hip_bf16.h>

#define V_NODES 100000
#define E_EDGES 600000
#define D_FEAT  128
#define VD      ((size_t)V_NODES * D_FEAT)

// ---------------------------------------------------------------------------
// Weight pre-transpose: wt[m][k*128+j] = W[m][j*128+k]   (m = 2*layer + sel)
// ---------------------------------------------------------------------------
__global__ void transpose_w_kernel(const float* __restrict__ W0,
                                   const float* __restrict__ W1,
                                   float* __restrict__ wt) {
    int m = blockIdx.y;            // 0..7
    int l = m >> 1, s = m & 1;
    const float* W = (s ? W1 : W0) + (size_t)l * 16384;
    float* T = wt + (size_t)m * 16384;
    int i = blockIdx.x * 256 + threadIdx.x;   // 0..16383
    int k = i >> 7, j = i & 127;
    T[k * 128 + j] = W[j * 128 + k];
}

// ---------------------------------------------------------------------------
// Dual GEMM: out[i][j] = sum_k x[i][k] * W[j][k] + bias[j]
// ---------------------------------------------------------------------------
__global__ __launch_bounds__(256) void gemm_dual_kernel(
    const float* __restrict__ x,
    const float* __restrict__ wt0, const float* __restrict__ bias0, float* __restrict__ out0,
    const float* __restrict__ wt1, const float* __restrict__ bias1, float* __restrict__ out1,
    int V) {
    const float* wt   = (blockIdx.y == 0) ? wt0   : wt1;
    const float* bias = (blockIdx.y == 0) ? bias0 : bias1;
    float*       out  = (blockIdx.y == 0) ? out0  : out1;

    __shared__ float xs[64 * 132];           // xs[r][k], stride 132 (16B aligned)
    const int t  = threadIdx.x;
    const int m0 = blockIdx.x * 64;

#pragma unroll
    for (int it = 0; it < 8; ++it) {
        int i  = it * 256 + t;               // 0..2047 float4 slots
        int c4 = i & 31;
        int r  = i >> 5;
        float4 v = make_float4(0.f, 0.f, 0.f, 0.f);
        int row = m0 + r;
        if (row < V)
            v = reinterpret_cast<const float4*>(x + (size_t)row * 128)[c4];
        *reinterpret_cast<float4*>(&xs[r * 132 + c4 * 4]) = v;
    }
    __syncthreads();

    const int cg = t & 15;                   // cols 8*cg..8*cg+7
    const int rg = t >> 4;                   // rows 4*rg..4*rg+3

    float acc[4][8];
#pragma unroll
    for (int i = 0; i < 4; ++i)
#pragma unroll
        for (int j = 0; j < 8; ++j) acc[i][j] = 0.f;

    for (int k4 = 0; k4 < 32; ++k4) {
        alignas(16) float a[4][4];
#pragma unroll
        for (int i = 0; i < 4; ++i)
            *reinterpret_cast<float4*>(a[i]) =
                *reinterpret_cast<const float4*>(&xs[(rg * 4 + i) * 132 + k4 * 4]);
#pragma unroll
        for (int kk = 0; kk < 4; ++kk) {
            alignas(16) float bv[8];
            *reinterpret_cast<float4*>(bv) =
                *reinterpret_cast<const float4*>(&wt[(k4 * 4 + kk) * 128 + cg * 8]);
            *reinterpret_cast<float4*>(bv + 4) =
                *reinterpret_cast<const float4*>(&wt[(k4 * 4 + kk) * 128 + cg * 8 + 4]);
#pragma unroll
            for (int i = 0; i < 4; ++i)
#pragma unroll
                for (int j = 0; j < 8; ++j)
                    acc[i][j] += a[i][kk] * bv[j];
        }
    }

    alignas(16) float bvv[8];
    *reinterpret_cast<float4*>(bvv)     = *reinterpret_cast<const float4*>(&bias[cg * 8]);
    *reinterpret_cast<float4*>(bvv + 4) = *reinterpret_cast<const float4*>(&bias[cg * 8 + 4]);

#pragma unroll
    for (int i = 0; i < 4; ++i) {
        int row = m0 + rg * 4 + i;
        if (row < V) {
            alignas(16) float o[8];
#pragma unroll
            for (int j = 0; j < 8; ++j) o[j] = acc[i][j] + bvv[j];
            *reinterpret_cast<float4*>(&out[(size_t)row * 128 + cg * 8]) =
                *reinterpret_cast<const float4*>(o);
            *reinterpret_cast<float4*>(&out[(size_t)row * 128 + cg * 8 + 4]) =
                *reinterpret_cast<const float4*>(o + 4);
        }
    }
}

// ---------------------------------------------------------------------------
// CSR construction — multi-block scan
// ---------------------------------------------------------------------------
__global__ void zero_int_kernel(int* __restrict__ p, int n) {
    int i = blockIdx.x * 256 + threadIdx.x;
    if (i < n) p[i] = 0;
}

__global__ __launch_bounds__(256) void degree_kernel(
    const int* __restrict__ edges, int* __restrict__ deg, int E) {
    int i = blockIdx.x * 256 + threadIdx.x;
    if (i >= E) return;
    atomicAdd(&deg[edges[2 * i]], 1);
    atomicAdd(&deg[edges[2 * i + 1]], 1);
}

// phase 1: per-block sums of deg
__global__ __launch_bounds__(256) void block_sum_kernel(
    const int* __restrict__ deg, int* __restrict__ bsums, int V) {
    __shared__ int sh[256];
    int i = blockIdx.x * 256 + threadIdx.x;
    sh[threadIdx.x] = (i < V) ? deg[i] : 0;
    __syncthreads();
    for (int off = 128; off > 0; off >>= 1) {
        if (threadIdx.x < off) sh[threadIdx.x] += sh[threadIdx.x + off];
        __syncthreads();
    }
    if (threadIdx.x == 0) bsums[blockIdx.x] = sh[0];
}

// phase 2: exclusive scan of block sums (nb <= 512), single block
__global__ __launch_bounds__(512) void scan_bsums_kernel(int* __restrict__ bsums, int nb) {
    __shared__ int sh[512];
    int t = threadIdx.x;
    int v = (t < nb) ? bsums[t] : 0;
    sh[t] = v;
    __syncthreads();
    for (int off = 1; off < 512; off <<= 1) {
        int add = (t >= off) ? sh[t - off] : 0;
        __syncthreads();
        sh[t] += add;
        __syncthreads();
    }
    if (t < nb) bsums[t] = sh[t] - v;   // exclusive
}

// phase 3: local exclusive scan + block offset -> offsets & cursor
__global__ __launch_bounds__(256) void offsets_kernel(
    const int* __restrict__ deg, const int* __restrict__ bsums,
    int* __restrict__ offsets, int* __restrict__ cursor, int V) {
    __shared__ int sh[256];
    int t = threadIdx.x;
    int i = blockIdx.x * 256 + t;
    int v = (i < V) ? deg[i] : 0;
    sh[t] = v;
    __syncthreads();
    for (int off = 1; off < 256; off <<= 1) {
        int add = (t >= off) ? sh[t - off] : 0;
        __syncthreads();
        sh[t] += add;
        __syncthreads();
    }
    int excl = sh[t] - v + bsums[blockIdx.x];
    if (i < V) { offsets[i] = excl; cursor[i] = excl; }
    if (i == V - 1) offsets[V] = excl + v;
}

__global__ __launch_bounds__(256) void fill_adj_kernel(
    const int* __restrict__ edges, int* __restrict__ cursor,
    int* __restrict__ adj, int E) {
    int i = blockIdx.x * 256 + threadIdx.x;
    if (i >= E) return;
    int a = edges[2 * i], b = edges[2 * i + 1];
    int pa = atomicAdd(&cursor[a], 1);
    adj[pa] = b;
    int pb = atomicAdd(&cursor[b], 1);
    adj[pb] = a;
}

// ---------------------------------------------------------------------------
// Gather: out[v] += sum over neighbors u of y[u].   32 lanes (float4) / node.
// ---------------------------------------------------------------------------
__global__ __launch_bounds__(256) void gather_kernel(
    const float* __restrict__ y, const int* __restrict__ offsets,
    const int* __restrict__ adj, float* __restrict__ out, int V) {
    const int t    = threadIdx.x;
    const int node = blockIdx.x * 8 + (t >> 5);
    if (node >= V) return;
    const int c4 = t & 31;
    int start = offsets[node], end = offsets[node + 1];

    float4 acc0 = make_float4(0.f, 0.f, 0.f, 0.f);
    float4 acc1 = make_float4(0.f, 0.f, 0.f, 0.f);
    int i = start;
    for (; i + 1 < end; i += 2) {
        int u0 = adj[i], u1 = adj[i + 1];
        float4 v0 = *reinterpret_cast<const float4*>(&y[(size_t)u0 * 128 + c4 * 4]);
        float4 v1 = *reinterpret_cast<const float4*>(&y[(size_t)u1 * 128 + c4 * 4]);
        acc0.x += v0.x; acc0.y += v0.y; acc0.z += v0.z; acc0.w += v0.w;
        acc1.x += v1.x; acc1.y += v1.y; acc1.z += v1.z; acc1.w += v1.w;
    }
    if (i < end) {
        int u0 = adj[i];
        float4 v0 = *reinterpret_cast<const float4*>(&y[(size_t)u0 * 128 + c4 * 4]);
        acc0.x += v0.x; acc0.y += v0.y; acc0.z += v0.z; acc0.w += v0.w;
    }
    float* op = &out[(size_t)node * 128 + c4 * 4];
    float4 o = *reinterpret_cast<const float4*>(op);
    o.x += acc0.x + acc1.x; o.y += acc0.y + acc1.y;
    o.z += acc0.z + acc1.z; o.w += acc0.w + acc1.w;
    *reinterpret_cast<float4*>(op) = o;
}

// ---------------------------------------------------------------------------
// BN
// ---------------------------------------------------------------------------
__global__ void zero_kernel(float* __restrict__ p, int n) {
    int i = blockIdx.x * 256 + threadIdx.x;
    if (i < n) p[i] = 0.f;
}

__global__ __launch_bounds__(256) void bn_stats_kernel(
    const float* __restrict__ x, float* __restrict__ stats, int V, int rows_pb) {
    const int t    = threadIdx.x;
    const int col  = t & 127;
    const int half = t >> 7;
    int r0 = blockIdx.x * rows_pb;
    int r1 = min(V, r0 + rows_pb);
    float s = 0.f, ss = 0.f;
    for (int r = r0 + half; r < r1; r += 2) {
        float v = x[(size_t)r * 128 + col];
        s += v;
        ss += v * v;
    }
    __shared__ float sh[256];
    sh[t] = s;
    __syncthreads();
    if (t < 128) atomicAdd(&stats[t], sh[t] + sh[t + 128]);
    __syncthreads();
    sh[t] = ss;
    __syncthreads();
    if (t < 128) atomicAdd(&stats[128 + t], sh[t] + sh[t + 128]);
}

__global__ __launch_bounds__(256) void bn_norm_relu_kernel(
    const float* __restrict__ x, const float* __restrict__ stats,
    const float* __restrict__ gamma, const float* __restrict__ beta,
    const float* __restrict__ res, float* __restrict__ outp, int V) {
    size_t idx = (size_t)blockIdx.x * 256 + threadIdx.x;   // float4 index
    size_t n4  = (size_t)V * 32;
    if (idx >= n4) return;
    int c4  = (int)(idx & 31);
    int col = c4 * 4;
    const float inv = 1.0f / (float)V;
    float4 v   = reinterpret_cast<const float4*>(x)[idx];
    float4 sum = *reinterpret_cast<const float4*>(&stats[col]);
    float4 ssq = *reinterpret_cast<const float4*>(&stats[128 + col]);
    float4 g   = *reinterpret_cast<const float4*>(&gamma[col]);
    float4 bb  = *reinterpret_cast<const float4*>(&beta[col]);

    float4 o;
    {
        float mu = sum.x * inv; float var = ssq.x * inv - mu * mu;
        float sc = g.x * rsqrtf(var + 1e-5f); o.x = v.x * sc + (bb.x - mu * sc);
    }
    {
        float mu = sum.y * inv; float var = ssq.y * inv - mu * mu;
        float sc = g.y * rsqrtf(var + 1e-5f); o.y = v.y * sc + (bb.y - mu * sc);
    }
    {
        float mu = sum.z * inv; float var = ssq.z * inv - mu * mu;
        float sc = g.z * rsqrtf(var + 1e-5f); o.z = v.z * sc + (bb.z - mu * sc);
    }
    {
        float mu = sum.w * inv; float var = ssq.w * inv - mu * mu;
        float sc = g.w * rsqrtf(var + 1e-5f); o.w = v.w * sc + (bb.w - mu * sc);
    }
    if (res) {
        float4 rv = reinterpret_cast<const float4*>(res)[idx];
        o.x += rv.x; o.y += rv.y; o.z += rv.z; o.w += rv.w;
    }
    o.x = fmaxf(o.x, 0.f); o.y = fmaxf(o.y, 0.f);
    o.z = fmaxf(o.z, 0.f); o.w = fmaxf(o.w, 0.f);
    reinterpret_cast<float4*>(outp)[idx] = o;
}

// ---------------------------------------------------------------------------
extern "C" void kernel_launch(void* const* d_in, const int* in_sizes, int n_in,
                              void* d_out, int out_size, void* d_ws, size_t ws_size,
                              hipStream_t stream) {
    const float* feat  = (const float*)d_in[0];
    const int*   edges = (const int*)d_in[1];
    const float* W0    = (const float*)d_in[2];
    const float* b0    = (const float*)d_in[3];
    const float* W1    = (const float*)d_in[4];
    const float* b1    = (const float*)d_in[5];
    const float* gamma = (const float*)d_in[6];
    const float* beta  = (const float*)d_in[7];
    float* out = (float*)d_out;

    float* buf_f = (float*)d_ws;           // [V,128] normalized activations
    float* buf_y = buf_f + VD;             // [V,128] neighbor-message features
    float* wt    = buf_y + VD;             // 8 x 128 x 128 transposed weights
    float* stats = wt + 8 * 16384;         // 3 x 256 floats
    int*   deg     = (int*)(stats + 768);  // V
    int*   offsets = deg + V_NODES;        // V+1
    int*   cursor  = offsets + V_NODES + 1;// V
    int*   bsums   = cursor + V_NODES;     // <=512
    int*   adj     = bsums + 512;          // 2E

    const int V = V_NODES, E = E_EDGES;
    const int gemm_blocks = (V + 63) / 64;
    const int gath_blocks = (V + 7) / 8;
    const int norm_blocks = (int)(((size_t)V * 32 + 255) / 256);
    const int stat_grid   = 1024;
    const int rows_pb     = (V + stat_grid - 1) / stat_grid;
    const int vblocks     = (V + 255) / 256;   // 391
    const int eblocks     = (E + 255) / 256;

    // Per-launch prep: weight transpose + CSR build + BN stats zero
    transpose_w_kernel<<<dim3(64, 8), 256, 0, stream>>>(W0, W1, wt);
    zero_int_kernel<<<vblocks, 256, 0, stream>>>(deg, V);
    zero_kernel<<<3, 256, 0, stream>>>(stats, 768);
    degree_kernel<<<eblocks, 256, 0, stream>>>(edges, deg, E);
    block_sum_kernel<<<vblocks, 256, 0, stream>>>(deg, bsums, V);
    scan_bsums_kernel<<<1, 512, 0, stream>>>(bsums, vblocks);
    offsets_kernel<<<vblocks, 256, 0, stream>>>(deg, bsums, offsets, cursor, V);
    fill_adj_kernel<<<eblocks, 256, 0, stream>>>(edges, cursor, adj, E);

    const float* x = feat;
    for (int l = 0; l < 4; ++l) {
        gemm_dual_kernel<<<dim3(gemm_blocks, 2), 256, 0, stream>>>(
            x,
            wt + (size_t)(2 * l) * 16384,     b0 + l * 128, out,
            wt + (size_t)(2 * l + 1) * 16384, b1 + l * 128, buf_y,
            V);
        gather_kernel<<<gath_blocks, 256, 0, stream>>>(buf_y, offsets, adj, out, V);
        if (l < 3) {
            bn_stats_kernel<<<stat_grid, 256, 0, stream>>>(out, stats + l * 256, V, rows_pb);
            bn_norm_relu_kernel<<<norm_blocks, 256, 0, stream>>>(
                out, stats + l * 256, gamma + l * 128, beta + l * 128,
                (l == 2) ? feat : nullptr, buf_f, V);
            x = buf_f;
        }
    }
}

// Round 4
// 789.833 us; speedup vs baseline: 11.1578x; 1.5685x over previous
//
#include <hip/hip_runtime.h>
#include <hip/hip_bf16.h>

#define V_NODES 100000
#define E_EDGES 600000
#define D_FEAT  128
#define VD      ((size_t)V_NODES * D_FEAT)

typedef short bf16x8 __attribute__((ext_vector_type(8)));
typedef float f32x4  __attribute__((ext_vector_type(4)));

__device__ inline unsigned short f2bf(float f) {
    __hip_bfloat16 h = __float2bfloat16(f);
    unsigned short u;
    __builtin_memcpy(&u, &h, 2);
    return u;
}

// ---------------------------------------------------------------------------
// Pack weights into bf16 MFMA B-fragment order:
// wp[m][ ((s*8 + c)*64 + lane)*8 + j ] = W[c*16 + (lane&15)][s*32 + (lane>>4)*8 + j]
// (m = 2*layer + sel; out[i][n] = sum_k x[i][k] * W[n][k])
// ---------------------------------------------------------------------------
__global__ void pack_w_kernel(const float* __restrict__ W0,
                              const float* __restrict__ W1,
                              unsigned short* __restrict__ wp) {
    int m = blockIdx.y;            // 0..7
    int l = m >> 1, sel = m & 1;
    const float* W = (sel ? W1 : W0) + (size_t)l * 16384;
    int i = blockIdx.x * 256 + threadIdx.x;   // 0..16383
    int j    = i & 7;
    int lane = (i >> 3) & 63;
    int c    = (i >> 9) & 7;
    int s    = i >> 12;
    int n0 = lane & 15, q = lane >> 4;
    float v = W[(c * 16 + n0) * 128 + s * 32 + q * 8 + j];
    wp[(size_t)m * 16384 + i] = f2bf(v);
}

// ---------------------------------------------------------------------------
// fp32 -> bf16 conversion (feat -> xb), one float4 per thread
// ---------------------------------------------------------------------------
__global__ __launch_bounds__(256) void cvt_bf16_kernel(
    const float* __restrict__ x, unsigned short* __restrict__ xb, size_t n4) {
    size_t i = (size_t)blockIdx.x * 256 + threadIdx.x;
    if (i >= n4) return;
    float4 v = reinterpret_cast<const float4*>(x)[i];
    ushort4 h;
    h.x = f2bf(v.x); h.y = f2bf(v.y); h.z = f2bf(v.z); h.w = f2bf(v.w);
    reinterpret_cast<ushort4*>(xb)[i] = h;
}

// ---------------------------------------------------------------------------
// MFMA dual GEMM: 64 rows/block (4 waves x 16 rows), full 128 cols, K=128.
// blockIdx.y==0 -> h0 (fp32, out0);  ==1 -> y (bf16, yb)
// ---------------------------------------------------------------------------
__global__ __launch_bounds__(256) void gemm_mfma_kernel(
    const unsigned short* __restrict__ xb,
    const unsigned short* __restrict__ wp0, const float* __restrict__ bias0,
    float* __restrict__ out0,
    const unsigned short* __restrict__ wp1, const float* __restrict__ bias1,
    unsigned short* __restrict__ yb,
    int V) {
    const bool sel = (blockIdx.y != 0);
    const unsigned short* wp   = sel ? wp1   : wp0;
    const float*          bias = sel ? bias1 : bias0;

    const int t    = threadIdx.x;
    const int wave = t >> 6;
    const int lane = t & 63;
    const int n0   = lane & 15;
    const int q    = lane >> 4;

    // A fragments: this lane supplies row (m0 + n0), k = s*32 + q*8 .. +8
    const int arow = blockIdx.x * 64 + wave * 16 + n0;
    bf16x8 a[4];
    if (arow < V) {
        const unsigned short* xr = xb + (size_t)arow * 128;
#pragma unroll
        for (int s = 0; s < 4; ++s)
            a[s] = *reinterpret_cast<const bf16x8*>(xr + s * 32 + q * 8);
    } else {
        bf16x8 z = {0, 0, 0, 0, 0, 0, 0, 0};
#pragma unroll
        for (int s = 0; s < 4; ++s) a[s] = z;
    }

    f32x4 acc[8];
    f32x4 z4 = {0.f, 0.f, 0.f, 0.f};
#pragma unroll
    for (int c = 0; c < 8; ++c) acc[c] = z4;

#pragma unroll
    for (int c = 0; c < 8; ++c) {
#pragma unroll
        for (int s = 0; s < 4; ++s) {
            bf16x8 b = *reinterpret_cast<const bf16x8*>(
                wp + ((size_t)((s * 8 + c) * 64 + lane)) * 8);
            acc[c] = __builtin_amdgcn_mfma_f32_16x16x32_bf16(a[s], b, acc[c], 0, 0, 0);
        }
    }

    // C/D layout: col = lane&15 (n0), row = q*4 + reg
    const int orow0 = blockIdx.x * 64 + wave * 16 + q * 4;
#pragma unroll
    for (int c = 0; c < 8; ++c) {
        float bv = bias[c * 16 + n0];
#pragma unroll
        for (int r = 0; r < 4; ++r) {
            int orow = orow0 + r;
            if (orow < V) {
                float val = acc[c][r] + bv;
                size_t idx = (size_t)orow * 128 + c * 16 + n0;
                if (!sel) out0[idx] = val;
                else      yb[idx]   = f2bf(val);
            }
        }
    }
}

// ---------------------------------------------------------------------------
// CSR construction — multi-block scan
// ---------------------------------------------------------------------------
__global__ void zero_int_kernel(int* __restrict__ p, int n) {
    int i = blockIdx.x * 256 + threadIdx.x;
    if (i < n) p[i] = 0;
}

__global__ __launch_bounds__(256) void degree_kernel(
    const int* __restrict__ edges, int* __restrict__ deg, int E) {
    int i = blockIdx.x * 256 + threadIdx.x;
    if (i >= E) return;
    atomicAdd(&deg[edges[2 * i]], 1);
    atomicAdd(&deg[edges[2 * i + 1]], 1);
}

__global__ __launch_bounds__(256) void block_sum_kernel(
    const int* __restrict__ deg, int* __restrict__ bsums, int V) {
    __shared__ int sh[256];
    int i = blockIdx.x * 256 + threadIdx.x;
    sh[threadIdx.x] = (i < V) ? deg[i] : 0;
    __syncthreads();
    for (int off = 128; off > 0; off >>= 1) {
        if (threadIdx.x < off) sh[threadIdx.x] += sh[threadIdx.x + off];
        __syncthreads();
    }
    if (threadIdx.x == 0) bsums[blockIdx.x] = sh[0];
}

__global__ __launch_bounds__(512) void scan_bsums_kernel(int* __restrict__ bsums, int nb) {
    __shared__ int sh[512];
    int t = threadIdx.x;
    int v = (t < nb) ? bsums[t] : 0;
    sh[t] = v;
    __syncthreads();
    for (int off = 1; off < 512; off <<= 1) {
        int add = (t >= off) ? sh[t - off] : 0;
        __syncthreads();
        sh[t] += add;
        __syncthreads();
    }
    if (t < nb) bsums[t] = sh[t] - v;   // exclusive
}

__global__ __launch_bounds__(256) void offsets_kernel(
    const int* __restrict__ deg, const int* __restrict__ bsums,
    int* __restrict__ offsets, int* __restrict__ cursor, int V) {
    __shared__ int sh[256];
    int t = threadIdx.x;
    int i = blockIdx.x * 256 + t;
    int v = (i < V) ? deg[i] : 0;
    sh[t] = v;
    __syncthreads();
    for (int off = 1; off < 256; off <<= 1) {
        int add = (t >= off) ? sh[t - off] : 0;
        __syncthreads();
        sh[t] += add;
        __syncthreads();
    }
    int excl = sh[t] - v + bsums[blockIdx.x];
    if (i < V) { offsets[i] = excl; cursor[i] = excl; }
    if (i == V - 1) offsets[V] = excl + v;
}

__global__ __launch_bounds__(256) void fill_adj_kernel(
    const int* __restrict__ edges, int* __restrict__ cursor,
    int* __restrict__ adj, int E) {
    int i = blockIdx.x * 256 + threadIdx.x;
    if (i >= E) return;
    int a = edges[2 * i], b = edges[2 * i + 1];
    int pa = atomicAdd(&cursor[a], 1);
    adj[pa] = b;
    int pb = atomicAdd(&cursor[b], 1);
    adj[pb] = a;
}

// ---------------------------------------------------------------------------
// Gather (bf16 y): out[v] += sum over neighbors u of y[u].
// 16 lanes/node, 8 cols/lane (16B bf16 load per neighbor).
// ---------------------------------------------------------------------------
__global__ __launch_bounds__(256) void gather_kernel(
    const unsigned short* __restrict__ yb, const int* __restrict__ offsets,
    const int* __restrict__ adj, float* __restrict__ out, int V) {
    const int t    = threadIdx.x;
    const int node = blockIdx.x * 16 + (t >> 4);
    if (node >= V) return;
    const int l8 = t & 15;                 // cols l8*8 .. +7
    int start = offsets[node], end = offsets[node + 1];

    float acc[8];
#pragma unroll
    for (int k = 0; k < 8; ++k) acc[k] = 0.f;

    int i = start;
    for (; i + 1 < end; i += 2) {
        int u0 = adj[i], u1 = adj[i + 1];
        uint4 p0 = *reinterpret_cast<const uint4*>(yb + (size_t)u0 * 128 + l8 * 8);
        uint4 p1 = *reinterpret_cast<const uint4*>(yb + (size_t)u1 * 128 + l8 * 8);
        acc[0] += __uint_as_float(p0.x << 16); acc[1] += __uint_as_float(p0.x & 0xffff0000u);
        acc[2] += __uint_as_float(p0.y << 16); acc[3] += __uint_as_float(p0.y & 0xffff0000u);
        acc[4] += __uint_as_float(p0.z << 16); acc[5] += __uint_as_float(p0.z & 0xffff0000u);
        acc[6] += __uint_as_float(p0.w << 16); acc[7] += __uint_as_float(p0.w & 0xffff0000u);
        acc[0] += __uint_as_float(p1.x << 16); acc[1] += __uint_as_float(p1.x & 0xffff0000u);
        acc[2] += __uint_as_float(p1.y << 16); acc[3] += __uint_as_float(p1.y & 0xffff0000u);
        acc[4] += __uint_as_float(p1.z << 16); acc[5] += __uint_as_float(p1.z & 0xffff0000u);
        acc[6] += __uint_as_float(p1.w << 16); acc[7] += __uint_as_float(p1.w & 0xffff0000u);
    }
    if (i < end) {
        int u0 = adj[i];
        uint4 p0 = *reinterpret_cast<const uint4*>(yb + (size_t)u0 * 128 + l8 * 8);
        acc[0] += __uint_as_float(p0.x << 16); acc[1] += __uint_as_float(p0.x & 0xffff0000u);
        acc[2] += __uint_as_float(p0.y << 16); acc[3] += __uint_as_float(p0.y & 0xffff0000u);
        acc[4] += __uint_as_float(p0.z << 16); acc[5] += __uint_as_float(p0.z & 0xffff0000u);
        acc[6] += __uint_as_float(p0.w << 16); acc[7] += __uint_as_float(p0.w & 0xffff0000u);
    }

    float* op = &out[(size_t)node * 128 + l8 * 8];
    float4 o0 = reinterpret_cast<const float4*>(op)[0];
    float4 o1 = reinterpret_cast<const float4*>(op)[1];
    o0.x += acc[0]; o0.y += acc[1]; o0.z += acc[2]; o0.w += acc[3];
    o1.x += acc[4]; o1.y += acc[5]; o1.z += acc[6]; o1.w += acc[7];
    reinterpret_cast<float4*>(op)[0] = o0;
    reinterpret_cast<float4*>(op)[1] = o1;
}

// ---------------------------------------------------------------------------
// BN
// ---------------------------------------------------------------------------
__global__ void zero_kernel(float* __restrict__ p, int n) {
    int i = blockIdx.x * 256 + threadIdx.x;
    if (i < n) p[i] = 0.f;
}

__global__ __launch_bounds__(256) void bn_stats_kernel(
    const float* __restrict__ x, float* __restrict__ stats, int V, int rows_pb) {
    const int t    = threadIdx.x;
    const int col  = t & 127;
    const int half = t >> 7;
    int r0 = blockIdx.x * rows_pb;
    int r1 = min(V, r0 + rows_pb);
    float s = 0.f, ss = 0.f;
    for (int r = r0 + half; r < r1; r += 2) {
        float v = x[(size_t)r * 128 + col];
        s += v;
        ss += v * v;
    }
    __shared__ float sh[256];
    sh[t] = s;
    __syncthreads();
    if (t < 128) atomicAdd(&stats[t], sh[t] + sh[t + 128]);
    __syncthreads();
    sh[t] = ss;
    __syncthreads();
    if (t < 128) atomicAdd(&stats[128 + t], sh[t] + sh[t + 128]);
}

// Normalize + optional residual + ReLU; writes bf16 activations for next GEMM.
__global__ __launch_bounds__(256) void bn_norm_relu_kernel(
    const float* __restrict__ x, const float* __restrict__ stats,
    const float* __restrict__ gamma, const float* __restrict__ beta,
    const float* __restrict__ res, unsigned short* __restrict__ outp, int V) {
    size_t idx = (size_t)blockIdx.x * 256 + threadIdx.x;   // float4 index
    size_t n4  = (size_t)V * 32;
    if (idx >= n4) return;
    int c4  = (int)(idx & 31);
    int col = c4 * 4;
    const float inv = 1.0f / (float)V;
    float4 v   = reinterpret_cast<const float4*>(x)[idx];
    float4 sum = *reinterpret_cast<const float4*>(&stats[col]);
    float4 ssq = *reinterpret_cast<const float4*>(&stats[128 + col]);
    float4 g   = *reinterpret_cast<const float4*>(&gamma[col]);
    float4 bb  = *reinterpret_cast<const float4*>(&beta[col]);

    float4 o;
    {
        float mu = sum.x * inv; float var = ssq.x * inv - mu * mu;
        float sc = g.x * rsqrtf(var + 1e-5f); o.x = v.x * sc + (bb.x - mu * sc);
    }
    {
        float mu = sum.y * inv; float var = ssq.y * inv - mu * mu;
        float sc = g.y * rsqrtf(var + 1e-5f); o.y = v.y * sc + (bb.y - mu * sc);
    }
    {
        float mu = sum.z * inv; float var = ssq.z * inv - mu * mu;
        float sc = g.z * rsqrtf(var + 1e-5f); o.z = v.z * sc + (bb.z - mu * sc);
    }
    {
        float mu = sum.w * inv; float var = ssq.w * inv - mu * mu;
        float sc = g.w * rsqrtf(var + 1e-5f); o.w = v.w * sc + (bb.w - mu * sc);
    }
    if (res) {
        float4 rv = reinterpret_cast<const float4*>(res)[idx];
        o.x += rv.x; o.y += rv.y; o.z += rv.z; o.w += rv.w;
    }
    ushort4 h;
    h.x = f2bf(fmaxf(o.x, 0.f)); h.y = f2bf(fmaxf(o.y, 0.f));
    h.z = f2bf(fmaxf(o.z, 0.f)); h.w = f2bf(fmaxf(o.w, 0.f));
    reinterpret_cast<ushort4*>(outp)[idx] = h;
}

// ---------------------------------------------------------------------------
extern "C" void kernel_launch(void* const* d_in, const int* in_sizes, int n_in,
                              void* d_out, int out_size, void* d_ws, size_t ws_size,
                              hipStream_t stream) {
    const float* feat  = (const float*)d_in[0];
    const int*   edges = (const int*)d_in[1];
    const float* W0    = (const float*)d_in[2];
    const float* b0    = (const float*)d_in[3];
    const float* W1    = (const float*)d_in[4];
    const float* b1    = (const float*)d_in[5];
    const float* gamma = (const float*)d_in[6];
    const float* beta  = (const float*)d_in[7];
    float* out = (float*)d_out;

    unsigned short* xb = (unsigned short*)d_ws;   // [V,128] bf16 activations
    unsigned short* yb = xb + VD;                 // [V,128] bf16 messages
    unsigned short* wp = yb + VD;                 // 8 x 16384 bf16 packed weights
    float* stats   = (float*)(wp + 8 * 16384);    // 3 x 256 floats
    int*   deg     = (int*)(stats + 768);         // V
    int*   offsets = deg + V_NODES;               // V+1
    int*   cursor  = offsets + V_NODES + 1;       // V
    int*   bsums   = cursor + V_NODES;            // <=512
    int*   adj     = bsums + 512;                 // 2E

    const int V = V_NODES, E = E_EDGES;
    const int gemm_blocks = (V + 63) / 64;
    const int gath_blocks = (V + 15) / 16;
    const int norm_blocks = (int)(((size_t)V * 32 + 255) / 256);
    const int stat_grid   = 1024;
    const int rows_pb     = (V + stat_grid - 1) / stat_grid;
    const int vblocks     = (V + 255) / 256;   // 391
    const int eblocks     = (E + 255) / 256;
    const int cvt_blocks  = (int)(((size_t)V * 32 + 255) / 256);

    // Per-launch prep: weight pack + feat->bf16 + CSR build + stats zero
    pack_w_kernel<<<dim3(64, 8), 256, 0, stream>>>(W0, W1, wp);
    cvt_bf16_kernel<<<cvt_blocks, 256, 0, stream>>>(feat, xb, (size_t)V * 32);
    zero_int_kernel<<<vblocks, 256, 0, stream>>>(deg, V);
    zero_kernel<<<3, 256, 0, stream>>>(stats, 768);
    degree_kernel<<<eblocks, 256, 0, stream>>>(edges, deg, E);
    block_sum_kernel<<<vblocks, 256, 0, stream>>>(deg, bsums, V);
    scan_bsums_kernel<<<1, 512, 0, stream>>>(bsums, vblocks);
    offsets_kernel<<<vblocks, 256, 0, stream>>>(deg, bsums, offsets, cursor, V);
    fill_adj_kernel<<<eblocks, 256, 0, stream>>>(edges, cursor, adj, E);

    for (int l = 0; l < 4; ++l) {
        gemm_mfma_kernel<<<dim3(gemm_blocks, 2), 256, 0, stream>>>(
            xb,
            wp + (size_t)(2 * l) * 16384,     b0 + l * 128, out,
            wp + (size_t)(2 * l + 1) * 16384, b1 + l * 128, yb,
            V);
        gather_kernel<<<gath_blocks, 256, 0, stream>>>(yb, offsets, adj, out, V);
        if (l < 3) {
            bn_stats_kernel<<<stat_grid, 256, 0, stream>>>(out, stats + l * 256, V, rows_pb);
            bn_norm_relu_kernel<<<norm_blocks, 256, 0, stream>>>(
                out, stats + l * 256, gamma + l * 128, beta + l * 128,
                (l == 2) ? feat : nullptr, xb, V);
        }
    }
}

// Round 5
// 654.048 us; speedup vs baseline: 13.4742x; 1.2076x over previous
//
#include <hip/hip_runtime.h>
#include <hip/hip_bf16.h>

#define V_NODES 100000
#define E_EDGES 600000
#define D_FEAT  128
#define VD      ((size_t)V_NODES * D_FEAT)
#define NREP    64

typedef short bf16x8 __attribute__((ext_vector_type(8)));
typedef float f32x4  __attribute__((ext_vector_type(4)));

__device__ inline unsigned short f2bf(float f) {
    __hip_bfloat16 h = __float2bfloat16(f);
    unsigned short u;
    __builtin_memcpy(&u, &h, 2);
    return u;
}

// ---------------------------------------------------------------------------
// Pack weights into bf16 MFMA B-fragment order (verified R4):
// wp[m][ ((s*8 + c)*64 + lane)*8 + j ] = W[c*16 + (lane&15)][s*32 + (lane>>4)*8 + j]
// ---------------------------------------------------------------------------
__global__ void pack_w_kernel(const float* __restrict__ W0,
                              const float* __restrict__ W1,
                              unsigned short* __restrict__ wp) {
    int m = blockIdx.y;            // 0..7
    int l = m >> 1, sel = m & 1;
    const float* W = (sel ? W1 : W0) + (size_t)l * 16384;
    int i = blockIdx.x * 256 + threadIdx.x;   // 0..16383
    int j    = i & 7;
    int lane = (i >> 3) & 63;
    int c    = (i >> 9) & 7;
    int s    = i >> 12;
    int n0 = lane & 15, q = lane >> 4;
    float v = W[(c * 16 + n0) * 128 + s * 32 + q * 8 + j];
    wp[(size_t)m * 16384 + i] = f2bf(v);
}

// ---------------------------------------------------------------------------
// Fused GEMM: A = relu(norm(xsrc) [+res]) built inline (bf16), both weight
// sets in one block (no out read/write race: block touches only its rows).
//   out0[i][n] = sum_k A[i][k]*W0[n][k] + b0[n]   (fp32)
//   yb[i][n]   = bf16( sum_k A[i][k]*W1[n][k] + b1[n] )
// ---------------------------------------------------------------------------
__global__ __launch_bounds__(256) void gemm_fused_kernel(
    const float* __restrict__ xsrc,
    const float* __restrict__ stats,   // null => no BN (layer 0)
    const float* __restrict__ gamma, const float* __restrict__ beta,
    const float* __restrict__ res,     // null unless layer 3
    const unsigned short* __restrict__ wp0, const float* __restrict__ bias0,
    float* __restrict__ out0,
    const unsigned short* __restrict__ wp1, const float* __restrict__ bias1,
    unsigned short* __restrict__ yb,
    int V) {
    __shared__ float lsc[128], lsh[128];
    const int t = threadIdx.x;
    if (stats) {
        if (t < 128) {
            float inv = 1.0f / (float)V;
            float mu  = stats[t] * inv;
            float var = stats[128 + t] * inv - mu * mu;
            float sc  = gamma[t] * rsqrtf(var + 1e-5f);
            lsc[t] = sc;
            lsh[t] = beta[t] - mu * sc;
        }
        __syncthreads();
    }

    const int wave = t >> 6;
    const int lane = t & 63;
    const int n0   = lane & 15;
    const int q    = lane >> 4;

    // A fragments: row (m0 + n0), k = s*32 + q*8 .. +8
    const int arow = blockIdx.x * 64 + wave * 16 + n0;
    bf16x8 a[4];
    {
        bf16x8 z = {0, 0, 0, 0, 0, 0, 0, 0};
#pragma unroll
        for (int s = 0; s < 4; ++s) a[s] = z;
    }
    if (arow < V) {
        const float* xr = xsrc + (size_t)arow * 128;
        const float* rr = res ? res + (size_t)arow * 128 : nullptr;
#pragma unroll
        for (int s = 0; s < 4; ++s) {
            int base = s * 32 + q * 8;
            float4 p0 = *reinterpret_cast<const float4*>(xr + base);
            float4 p1 = *reinterpret_cast<const float4*>(xr + base + 4);
            float v[8] = {p0.x, p0.y, p0.z, p0.w, p1.x, p1.y, p1.z, p1.w};
            if (stats) {
#pragma unroll
                for (int j = 0; j < 8; ++j)
                    v[j] = v[j] * lsc[base + j] + lsh[base + j];
                if (rr) {
                    float4 r0 = *reinterpret_cast<const float4*>(rr + base);
                    float4 r1 = *reinterpret_cast<const float4*>(rr + base + 4);
                    v[0] += r0.x; v[1] += r0.y; v[2] += r0.z; v[3] += r0.w;
                    v[4] += r1.x; v[5] += r1.y; v[6] += r1.z; v[7] += r1.w;
                }
#pragma unroll
                for (int j = 0; j < 8; ++j) v[j] = fmaxf(v[j], 0.f);
            }
            bf16x8 af;
#pragma unroll
            for (int j = 0; j < 8; ++j) af[j] = (short)f2bf(v[j]);
            a[s] = af;
        }
    }

    f32x4 acc0[8], acc1[8];
    f32x4 z4 = {0.f, 0.f, 0.f, 0.f};
#pragma unroll
    for (int c = 0; c < 8; ++c) { acc0[c] = z4; acc1[c] = z4; }

#pragma unroll
    for (int c = 0; c < 8; ++c) {
#pragma unroll
        for (int s = 0; s < 4; ++s) {
            size_t off = ((size_t)((s * 8 + c) * 64 + lane)) * 8;
            bf16x8 b0f = *reinterpret_cast<const bf16x8*>(wp0 + off);
            bf16x8 b1f = *reinterpret_cast<const bf16x8*>(wp1 + off);
            acc0[c] = __builtin_amdgcn_mfma_f32_16x16x32_bf16(a[s], b0f, acc0[c], 0, 0, 0);
            acc1[c] = __builtin_amdgcn_mfma_f32_16x16x32_bf16(a[s], b1f, acc1[c], 0, 0, 0);
        }
    }

    // All A-reads of this block's rows complete before we overwrite out rows.
    __syncthreads();

    // C/D layout: col = lane&15 (n0), row = q*4 + reg
    const int orow0 = blockIdx.x * 64 + wave * 16 + q * 4;
#pragma unroll
    for (int c = 0; c < 8; ++c) {
        float bv0 = bias0[c * 16 + n0];
        float bv1 = bias1[c * 16 + n0];
#pragma unroll
        for (int r = 0; r < 4; ++r) {
            int orow = orow0 + r;
            if (orow < V) {
                size_t idx = (size_t)orow * 128 + c * 16 + n0;
                out0[idx] = acc0[c][r] + bv0;
                yb[idx]   = f2bf(acc1[c][r] + bv1);
            }
        }
    }
}

// ---------------------------------------------------------------------------
// CSR construction — multi-block scan
// ---------------------------------------------------------------------------
__global__ void zero_int_kernel(int* __restrict__ p, int n) {
    int i = blockIdx.x * 256 + threadIdx.x;
    if (i < n) p[i] = 0;
}

__global__ __launch_bounds__(256) void degree_kernel(
    const int* __restrict__ edges, int* __restrict__ deg, int E) {
    int i = blockIdx.x * 256 + threadIdx.x;
    if (i >= E) return;
    atomicAdd(&deg[edges[2 * i]], 1);
    atomicAdd(&deg[edges[2 * i + 1]], 1);
}

__global__ __launch_bounds__(256) void block_sum_kernel(
    const int* __restrict__ deg, int* __restrict__ bsums, int V) {
    __shared__ int sh[256];
    int i = blockIdx.x * 256 + threadIdx.x;
    sh[threadIdx.x] = (i < V) ? deg[i] : 0;
    __syncthreads();
    for (int off = 128; off > 0; off >>= 1) {
        if (threadIdx.x < off) sh[threadIdx.x] += sh[threadIdx.x + off];
        __syncthreads();
    }
    if (threadIdx.x == 0) bsums[blockIdx.x] = sh[0];
}

__global__ __launch_bounds__(512) void scan_bsums_kernel(int* __restrict__ bsums, int nb) {
    __shared__ int sh[512];
    int t = threadIdx.x;
    int v = (t < nb) ? bsums[t] : 0;
    sh[t] = v;
    __syncthreads();
    for (int off = 1; off < 512; off <<= 1) {
        int add = (t >= off) ? sh[t - off] : 0;
        __syncthreads();
        sh[t] += add;
        __syncthreads();
    }
    if (t < nb) bsums[t] = sh[t] - v;   // exclusive
}

__global__ __launch_bounds__(256) void offsets_kernel(
    const int* __restrict__ deg, const int* __restrict__ bsums,
    int* __restrict__ offsets, int* __restrict__ cursor, int V) {
    __shared__ int sh[256];
    int t = threadIdx.x;
    int i = blockIdx.x * 256 + t;
    int v = (i < V) ? deg[i] : 0;
    sh[t] = v;
    __syncthreads();
    for (int off = 1; off < 256; off <<= 1) {
        int add = (t >= off) ? sh[t - off] : 0;
        __syncthreads();
        sh[t] += add;
        __syncthreads();
    }
    int excl = sh[t] - v + bsums[blockIdx.x];
    if (i < V) { offsets[i] = excl; cursor[i] = excl; }
    if (i == V - 1) offsets[V] = excl + v;
}

__global__ __launch_bounds__(256) void fill_adj_kernel(
    const int* __restrict__ edges, int* __restrict__ cursor,
    int* __restrict__ adj, int E) {
    int i = blockIdx.x * 256 + threadIdx.x;
    if (i >= E) return;
    int a = edges[2 * i], b = edges[2 * i + 1];
    int pa = atomicAdd(&cursor[a], 1);
    adj[pa] = b;
    int pb = atomicAdd(&cursor[b], 1);
    adj[pb] = a;
}

// ---------------------------------------------------------------------------
// Gather + fused BN stats.
// 16 lanes/node (8 bf16 cols/lane). After computing the final out row,
// shuffle+LDS reduce per-block col sums/ssq -> atomics into replica slot.
// ---------------------------------------------------------------------------
__global__ __launch_bounds__(256) void gather_stats_kernel(
    const unsigned short* __restrict__ yb, const int* __restrict__ offsets,
    const int* __restrict__ adj, float* __restrict__ out,
    float* __restrict__ rep, int V) {
    __shared__ float part[4][16][16];
    const int t    = threadIdx.x;
    const int node = blockIdx.x * 16 + (t >> 4);
    const int l8   = t & 15;                 // cols l8*8 .. +7

    float o[8];
#pragma unroll
    for (int k = 0; k < 8; ++k) o[k] = 0.f;

    if (node < V) {
        int start = offsets[node], end = offsets[node + 1];
        float acc[8];
#pragma unroll
        for (int k = 0; k < 8; ++k) acc[k] = 0.f;

        int i = start;
        for (; i + 1 < end; i += 2) {
            int u0 = adj[i], u1 = adj[i + 1];
            uint4 p0 = *reinterpret_cast<const uint4*>(yb + (size_t)u0 * 128 + l8 * 8);
            uint4 p1 = *reinterpret_cast<const uint4*>(yb + (size_t)u1 * 128 + l8 * 8);
            acc[0] += __uint_as_float(p0.x << 16); acc[1] += __uint_as_float(p0.x & 0xffff0000u);
            acc[2] += __uint_as_float(p0.y << 16); acc[3] += __uint_as_float(p0.y & 0xffff0000u);
            acc[4] += __uint_as_float(p0.z << 16); acc[5] += __uint_as_float(p0.z & 0xffff0000u);
            acc[6] += __uint_as_float(p0.w << 16); acc[7] += __uint_as_float(p0.w & 0xffff0000u);
            acc[0] += __uint_as_float(p1.x << 16); acc[1] += __uint_as_float(p1.x & 0xffff0000u);
            acc[2] += __uint_as_float(p1.y << 16); acc[3] += __uint_as_float(p1.y & 0xffff0000u);
            acc[4] += __uint_as_float(p1.z << 16); acc[5] += __uint_as_float(p1.z & 0xffff0000u);
            acc[6] += __uint_as_float(p1.w << 16); acc[7] += __uint_as_float(p1.w & 0xffff0000u);
        }
        if (i < end) {
            int u0 = adj[i];
            uint4 p0 = *reinterpret_cast<const uint4*>(yb + (size_t)u0 * 128 + l8 * 8);
            acc[0] += __uint_as_float(p0.x << 16); acc[1] += __uint_as_float(p0.x & 0xffff0000u);
            acc[2] += __uint_as_float(p0.y << 16); acc[3] += __uint_as_float(p0.y & 0xffff0000u);
            acc[4] += __uint_as_float(p0.z << 16); acc[5] += __uint_as_float(p0.z & 0xffff0000u);
            acc[6] += __uint_as_float(p0.w << 16); acc[7] += __uint_as_float(p0.w & 0xffff0000u);
        }

        float* op = &out[(size_t)node * 128 + l8 * 8];
        float4 o0 = reinterpret_cast<const float4*>(op)[0];
        float4 o1 = reinterpret_cast<const float4*>(op)[1];
        o[0] = o0.x + acc[0]; o[1] = o0.y + acc[1];
        o[2] = o0.z + acc[2]; o[3] = o0.w + acc[3];
        o[4] = o1.x + acc[4]; o[5] = o1.y + acc[5];
        o[6] = o1.z + acc[6]; o[7] = o1.w + acc[7];
        reinterpret_cast<float4*>(op)[0] = make_float4(o[0], o[1], o[2], o[3]);
        reinterpret_cast<float4*>(op)[1] = make_float4(o[4], o[5], o[6], o[7]);
    }

    if (rep) {
        const int lane = t & 63, wave = t >> 6;
        float s[8], qq[8];
#pragma unroll
        for (int k = 0; k < 8; ++k) { s[k] = o[k]; qq[k] = o[k] * o[k]; }
#pragma unroll
        for (int k = 0; k < 8; ++k) {
            s[k]  += __shfl_xor(s[k], 16);  qq[k] += __shfl_xor(qq[k], 16);
            s[k]  += __shfl_xor(s[k], 32);  qq[k] += __shfl_xor(qq[k], 32);
        }
        if (lane < 16) {
#pragma unroll
            for (int k = 0; k < 8; ++k) {
                part[wave][lane][k]     = s[k];
                part[wave][lane][8 + k] = qq[k];
            }
        }
        __syncthreads();
        int l8b = t >> 4, slot = t & 15;
        float tot = part[0][l8b][slot] + part[1][l8b][slot] +
                    part[2][l8b][slot] + part[3][l8b][slot];
        int col = l8b * 8 + (slot & 7);
        float* dst = rep + (size_t)(blockIdx.x & (NREP - 1)) * 256 +
                     (slot < 8 ? col : 128 + col);
        atomicAdd(dst, tot);
    }
}

// ---------------------------------------------------------------------------
// Reduce NREP stats replicas -> 256 final (sum[128], ssq[128])
// ---------------------------------------------------------------------------
__global__ void reduce_stats_kernel(const float* __restrict__ rep,
                                    float* __restrict__ sf) {
    int t = threadIdx.x;   // 256
    float s = 0.f;
#pragma unroll 8
    for (int r = 0; r < NREP; ++r) s += rep[r * 256 + t];
    sf[t] = s;
}

__global__ void zero_kernel(float* __restrict__ p, int n) {
    int i = blockIdx.x * 256 + threadIdx.x;
    if (i < n) p[i] = 0.f;
}

// ---------------------------------------------------------------------------
extern "C" void kernel_launch(void* const* d_in, const int* in_sizes, int n_in,
                              void* d_out, int out_size, void* d_ws, size_t ws_size,
                              hipStream_t stream) {
    const float* feat  = (const float*)d_in[0];
    const int*   edges = (const int*)d_in[1];
    const float* W0    = (const float*)d_in[2];
    const float* b0    = (const float*)d_in[3];
    const float* W1    = (const float*)d_in[4];
    const float* b1    = (const float*)d_in[5];
    const float* gamma = (const float*)d_in[6];
    const float* beta  = (const float*)d_in[7];
    float* out = (float*)d_out;

    unsigned short* yb = (unsigned short*)d_ws;   // [V,128] bf16 messages
    unsigned short* wp = yb + VD;                 // 8 x 16384 bf16 packed weights
    float* rep     = (float*)(wp + 8 * 16384);    // 3 x NREP x 256
    float* sf      = rep + 3 * NREP * 256;        // 3 x 256 final stats
    int*   deg     = (int*)(sf + 768);            // V
    int*   offsets = deg + V_NODES;               // V+1
    int*   cursor  = offsets + V_NODES + 1;       // V
    int*   bsums   = cursor + V_NODES;            // <=512
    int*   adj     = bsums + 512;                 // 2E

    const int V = V_NODES, E = E_EDGES;
    const int gemm_blocks = (V + 63) / 64;       // 1563
    const int gath_blocks = (V + 15) / 16;       // 6250
    const int vblocks     = (V + 255) / 256;     // 391
    const int eblocks     = (E + 255) / 256;
    const int rep_total   = 3 * NREP * 256;      // 49152

    // Per-launch prep
    pack_w_kernel<<<dim3(64, 8), 256, 0, stream>>>(W0, W1, wp);
    zero_kernel<<<(rep_total + 255) / 256, 256, 0, stream>>>(rep, rep_total);
    zero_int_kernel<<<vblocks, 256, 0, stream>>>(deg, V);
    degree_kernel<<<eblocks, 256, 0, stream>>>(edges, deg, E);
    block_sum_kernel<<<vblocks, 256, 0, stream>>>(deg, bsums, V);
    scan_bsums_kernel<<<1, 512, 0, stream>>>(bsums, vblocks);
    offsets_kernel<<<vblocks, 256, 0, stream>>>(deg, bsums, offsets, cursor, V);
    fill_adj_kernel<<<eblocks, 256, 0, stream>>>(edges, cursor, adj, E);

    for (int l = 0; l < 4; ++l) {
        const float* xsrc   = (l == 0) ? feat : out;
        const float* stats  = (l == 0) ? nullptr : sf + (size_t)(l - 1) * 256;
        const float* gam    = (l == 0) ? nullptr : gamma + (l - 1) * 128;
        const float* bet    = (l == 0) ? nullptr : beta + (l - 1) * 128;
        const float* res    = (l == 3) ? feat : nullptr;

        gemm_fused_kernel<<<gemm_blocks, 256, 0, stream>>>(
            xsrc, stats, gam, bet, res,
            wp + (size_t)(2 * l) * 16384,     b0 + l * 128, out,
            wp + (size_t)(2 * l + 1) * 16384, b1 + l * 128, yb,
            V);

        float* rep_l = (l < 3) ? rep + (size_t)l * NREP * 256 : nullptr;
        gather_stats_kernel<<<gath_blocks, 256, 0, stream>>>(
            yb, offsets, adj, out, rep_l, V);
        if (l < 3)
            reduce_stats_kernel<<<1, 256, 0, stream>>>(rep_l, sf + (size_t)l * 256);
    }
}

// Round 6
// 637.626 us; speedup vs baseline: 13.8213x; 1.0258x over previous
//
#include <hip/hip_runtime.h>
#include <hip/hip_bf16.h>

#define V_NODES 100000
#define E_EDGES 600000
#define D_FEAT  128
#define VD      ((size_t)V_NODES * D_FEAT)
#define NREP    64
#define PART_SZ 12500   // V/8 for XCD-aligned adj partitioning

typedef short bf16x8 __attribute__((ext_vector_type(8)));
typedef float f32x4  __attribute__((ext_vector_type(4)));

__device__ inline unsigned short f2bf(float f) {
    __hip_bfloat16 h = __float2bfloat16(f);
    unsigned short u;
    __builtin_memcpy(&u, &h, 2);
    return u;
}
__device__ inline float bfhi(unsigned int u) { return __uint_as_float(u & 0xffff0000u); }
__device__ inline float bflo(unsigned int u) { return __uint_as_float(u << 16); }

// ---------------------------------------------------------------------------
// Pack weights into bf16 MFMA B-fragment order (verified R4):
// wp[m][ ((s*8 + c)*64 + lane)*8 + j ] = W[c*16 + (lane&15)][s*32 + (lane>>4)*8 + j]
// ---------------------------------------------------------------------------
__global__ void pack_w_kernel(const float* __restrict__ W0,
                              const float* __restrict__ W1,
                              unsigned short* __restrict__ wp) {
    int m = blockIdx.y;            // 0..7
    int l = m >> 1, sel = m & 1;
    const float* W = (sel ? W1 : W0) + (size_t)l * 16384;
    int i = blockIdx.x * 256 + threadIdx.x;   // 0..16383
    int j    = i & 7;
    int lane = (i >> 3) & 63;
    int c    = (i >> 9) & 7;
    int s    = i >> 12;
    int n0 = lane & 15, q = lane >> 4;
    float v = W[(c * 16 + n0) * 128 + s * 32 + q * 8 + j];
    wp[(size_t)m * 16384 + i] = f2bf(v);
}

// ---------------------------------------------------------------------------
// Fused GEMM. A = relu(norm(x) [+res]) built inline as bf16 fragments.
// x source: xf (fp32, layer 0) or xh (bf16, layers 1-3). Output h0:
// outf (fp32, layer 3 = d_out) or outh (bf16 hb, layers 0-2). y -> yb bf16.
// Block reads only its own 64 rows, __syncthreads, then overwrites them.
// ---------------------------------------------------------------------------
__global__ __launch_bounds__(256) void gemm_fused_kernel(
    const float* __restrict__ xf, const unsigned short* __restrict__ xh,
    const float* __restrict__ stats,   // null => no BN (layer 0)
    const float* __restrict__ gamma, const float* __restrict__ beta,
    const float* __restrict__ res,     // null unless layer 3
    const unsigned short* __restrict__ wp0, const float* __restrict__ bias0,
    float* __restrict__ outf, unsigned short* __restrict__ outh,
    const unsigned short* __restrict__ wp1, const float* __restrict__ bias1,
    unsigned short* __restrict__ yb,
    int V) {
    __shared__ float lsc[128], lsh[128];
    const int t = threadIdx.x;
    if (stats) {
        if (t < 128) {
            float inv = 1.0f / (float)V;
            float mu  = stats[t] * inv;
            float var = stats[128 + t] * inv - mu * mu;
            float sc  = gamma[t] * rsqrtf(var + 1e-5f);
            lsc[t] = sc;
            lsh[t] = beta[t] - mu * sc;
        }
        __syncthreads();
    }

    const int wave = t >> 6;
    const int lane = t & 63;
    const int n0   = lane & 15;
    const int q    = lane >> 4;

    const int arow = blockIdx.x * 64 + wave * 16 + n0;
    bf16x8 a[4];
    {
        bf16x8 z = {0, 0, 0, 0, 0, 0, 0, 0};
#pragma unroll
        for (int s = 0; s < 4; ++s) a[s] = z;
    }
    if (arow < V) {
        const float* rr = res ? res + (size_t)arow * 128 : nullptr;
#pragma unroll
        for (int s = 0; s < 4; ++s) {
            int base = s * 32 + q * 8;
            float v[8];
            if (xh) {
                uint4 p = *reinterpret_cast<const uint4*>(xh + (size_t)arow * 128 + base);
                v[0] = bflo(p.x); v[1] = bfhi(p.x);
                v[2] = bflo(p.y); v[3] = bfhi(p.y);
                v[4] = bflo(p.z); v[5] = bfhi(p.z);
                v[6] = bflo(p.w); v[7] = bfhi(p.w);
            } else {
                const float* xr = xf + (size_t)arow * 128 + base;
                float4 p0 = *reinterpret_cast<const float4*>(xr);
                float4 p1 = *reinterpret_cast<const float4*>(xr + 4);
                v[0] = p0.x; v[1] = p0.y; v[2] = p0.z; v[3] = p0.w;
                v[4] = p1.x; v[5] = p1.y; v[6] = p1.z; v[7] = p1.w;
            }
            if (stats) {
#pragma unroll
                for (int j = 0; j < 8; ++j)
                    v[j] = v[j] * lsc[base + j] + lsh[base + j];
                if (rr) {
                    float4 r0 = *reinterpret_cast<const float4*>(rr + base);
                    float4 r1 = *reinterpret_cast<const float4*>(rr + base + 4);
                    v[0] += r0.x; v[1] += r0.y; v[2] += r0.z; v[3] += r0.w;
                    v[4] += r1.x; v[5] += r1.y; v[6] += r1.z; v[7] += r1.w;
                }
#pragma unroll
                for (int j = 0; j < 8; ++j) v[j] = fmaxf(v[j], 0.f);
            }
            bf16x8 af;
#pragma unroll
            for (int j = 0; j < 8; ++j) af[j] = (short)f2bf(v[j]);
            a[s] = af;
        }
    }

    f32x4 acc0[8], acc1[8];
    f32x4 z4 = {0.f, 0.f, 0.f, 0.f};
#pragma unroll
    for (int c = 0; c < 8; ++c) { acc0[c] = z4; acc1[c] = z4; }

#pragma unroll
    for (int c = 0; c < 8; ++c) {
#pragma unroll
        for (int s = 0; s < 4; ++s) {
            size_t off = ((size_t)((s * 8 + c) * 64 + lane)) * 8;
            bf16x8 b0f = *reinterpret_cast<const bf16x8*>(wp0 + off);
            bf16x8 b1f = *reinterpret_cast<const bf16x8*>(wp1 + off);
            acc0[c] = __builtin_amdgcn_mfma_f32_16x16x32_bf16(a[s], b0f, acc0[c], 0, 0, 0);
            acc1[c] = __builtin_amdgcn_mfma_f32_16x16x32_bf16(a[s], b1f, acc1[c], 0, 0, 0);
        }
    }

    // All A-reads of this block's rows complete before overwriting them.
    __syncthreads();

    // C/D layout: col = lane&15 (n0), row = q*4 + reg
    const int orow0 = blockIdx.x * 64 + wave * 16 + q * 4;
#pragma unroll
    for (int c = 0; c < 8; ++c) {
        float bv0 = bias0[c * 16 + n0];
        float bv1 = bias1[c * 16 + n0];
#pragma unroll
        for (int r = 0; r < 4; ++r) {
            int orow = orow0 + r;
            if (orow < V) {
                size_t idx = (size_t)orow * 128 + c * 16 + n0;
                float v0 = acc0[c][r] + bv0;
                if (outf) outf[idx] = v0;
                else      outh[idx] = f2bf(v0);
                yb[idx] = f2bf(acc1[c][r] + bv1);
            }
        }
    }
}

// ---------------------------------------------------------------------------
// CSR construction — multi-block scan
// ---------------------------------------------------------------------------
__global__ void zero_int_kernel(int* __restrict__ p, int n) {
    int i = blockIdx.x * 256 + threadIdx.x;
    if (i < n) p[i] = 0;
}

__global__ __launch_bounds__(256) void degree_kernel(
    const int* __restrict__ edges, int* __restrict__ deg, int E) {
    int i = blockIdx.x * 256 + threadIdx.x;
    if (i >= E) return;
    atomicAdd(&deg[edges[2 * i]], 1);
    atomicAdd(&deg[edges[2 * i + 1]], 1);
}

__global__ __launch_bounds__(256) void block_sum_kernel(
    const int* __restrict__ deg, int* __restrict__ bsums, int V) {
    __shared__ int sh[256];
    int i = blockIdx.x * 256 + threadIdx.x;
    sh[threadIdx.x] = (i < V) ? deg[i] : 0;
    __syncthreads();
    for (int off = 128; off > 0; off >>= 1) {
        if (threadIdx.x < off) sh[threadIdx.x] += sh[threadIdx.x + off];
        __syncthreads();
    }
    if (threadIdx.x == 0) bsums[blockIdx.x] = sh[0];
}

__global__ __launch_bounds__(512) void scan_bsums_kernel(int* __restrict__ bsums, int nb) {
    __shared__ int sh[512];
    int t = threadIdx.x;
    int v = (t < nb) ? bsums[t] : 0;
    sh[t] = v;
    __syncthreads();
    for (int off = 1; off < 512; off <<= 1) {
        int add = (t >= off) ? sh[t - off] : 0;
        __syncthreads();
        sh[t] += add;
        __syncthreads();
    }
    if (t < nb) bsums[t] = sh[t] - v;   // exclusive
}

__global__ __launch_bounds__(256) void offsets_kernel(
    const int* __restrict__ deg, const int* __restrict__ bsums,
    int* __restrict__ offsets, int* __restrict__ cursor, int V) {
    __shared__ int sh[256];
    int t = threadIdx.x;
    int i = blockIdx.x * 256 + t;
    int v = (i < V) ? deg[i] : 0;
    sh[t] = v;
    __syncthreads();
    for (int off = 1; off < 256; off <<= 1) {
        int add = (t >= off) ? sh[t - off] : 0;
        __syncthreads();
        sh[t] += add;
        __syncthreads();
    }
    int excl = sh[t] - v + bsums[blockIdx.x];
    if (i < V) { offsets[i] = excl; cursor[i] = excl; }
    if (i == V - 1) offsets[V] = excl + v;
}

// XCD-partitioned adj fill: block i handles partition (i&7), edge slice (i>>3).
// Writes to a given adj region come (heuristically) from one XCD only, so L2
// lines fill completely before eviction -> no partial-line writeback storm.
__global__ __launch_bounds__(256) void fill_adj_kernel(
    const int* __restrict__ edges, int* __restrict__ cursor,
    int* __restrict__ adj, int E) {
    int part = blockIdx.x & 7;
    int i = (blockIdx.x >> 3) * 256 + threadIdx.x;
    if (i >= E) return;
    int a = edges[2 * i], b = edges[2 * i + 1];
    if (a / PART_SZ == part) { int pa = atomicAdd(&cursor[a], 1); adj[pa] = b; }
    if (b / PART_SZ == part) { int pb = atomicAdd(&cursor[b], 1); adj[pb] = a; }
}

// ---------------------------------------------------------------------------
// Gather + fused BN stats. 16 lanes/node (8 bf16 cols/lane).
// Node-row update: outh (bf16, layers 0-2) or outf (fp32, layer 3).
// ---------------------------------------------------------------------------
__global__ __launch_bounds__(256) void gather_stats_kernel(
    const unsigned short* __restrict__ yb, const int* __restrict__ offsets,
    const int* __restrict__ adj,
    float* __restrict__ outf, unsigned short* __restrict__ outh,
    float* __restrict__ rep, int V) {
    __shared__ float part[4][16][16];
    const int t    = threadIdx.x;
    const int node = blockIdx.x * 16 + (t >> 4);
    const int l8   = t & 15;                 // cols l8*8 .. +7

    float o[8];
#pragma unroll
    for (int k = 0; k < 8; ++k) o[k] = 0.f;

    if (node < V) {
        int start = offsets[node], end = offsets[node + 1];
        float acc[8];
#pragma unroll
        for (int k = 0; k < 8; ++k) acc[k] = 0.f;

        int i = start;
        for (; i + 1 < end; i += 2) {
            int u0 = adj[i], u1 = adj[i + 1];
            uint4 p0 = *reinterpret_cast<const uint4*>(yb + (size_t)u0 * 128 + l8 * 8);
            uint4 p1 = *reinterpret_cast<const uint4*>(yb + (size_t)u1 * 128 + l8 * 8);
            acc[0] += bflo(p0.x); acc[1] += bfhi(p0.x);
            acc[2] += bflo(p0.y); acc[3] += bfhi(p0.y);
            acc[4] += bflo(p0.z); acc[5] += bfhi(p0.z);
            acc[6] += bflo(p0.w); acc[7] += bfhi(p0.w);
            acc[0] += bflo(p1.x); acc[1] += bfhi(p1.x);
            acc[2] += bflo(p1.y); acc[3] += bfhi(p1.y);
            acc[4] += bflo(p1.z); acc[5] += bfhi(p1.z);
            acc[6] += bflo(p1.w); acc[7] += bfhi(p1.w);
        }
        if (i < end) {
            int u0 = adj[i];
            uint4 p0 = *reinterpret_cast<const uint4*>(yb + (size_t)u0 * 128 + l8 * 8);
            acc[0] += bflo(p0.x); acc[1] += bfhi(p0.x);
            acc[2] += bflo(p0.y); acc[3] += bfhi(p0.y);
            acc[4] += bflo(p0.z); acc[5] += bfhi(p0.z);
            acc[6] += bflo(p0.w); acc[7] += bfhi(p0.w);
        }

        if (outh) {
            unsigned short* op = outh + (size_t)node * 128 + l8 * 8;
            uint4 h = *reinterpret_cast<const uint4*>(op);
            o[0] = bflo(h.x) + acc[0]; o[1] = bfhi(h.x) + acc[1];
            o[2] = bflo(h.y) + acc[2]; o[3] = bfhi(h.y) + acc[3];
            o[4] = bflo(h.z) + acc[4]; o[5] = bfhi(h.z) + acc[5];
            o[6] = bflo(h.w) + acc[6]; o[7] = bfhi(h.w) + acc[7];
            uint4 hn;
            hn.x = (unsigned)f2bf(o[0]) | ((unsigned)f2bf(o[1]) << 16);
            hn.y = (unsigned)f2bf(o[2]) | ((unsigned)f2bf(o[3]) << 16);
            hn.z = (unsigned)f2bf(o[4]) | ((unsigned)f2bf(o[5]) << 16);
            hn.w = (unsigned)f2bf(o[6]) | ((unsigned)f2bf(o[7]) << 16);
            *reinterpret_cast<uint4*>(op) = hn;
        } else {
            float* op = outf + (size_t)node * 128 + l8 * 8;
            float4 o0 = reinterpret_cast<const float4*>(op)[0];
            float4 o1 = reinterpret_cast<const float4*>(op)[1];
            o[0] = o0.x + acc[0]; o[1] = o0.y + acc[1];
            o[2] = o0.z + acc[2]; o[3] = o0.w + acc[3];
            o[4] = o1.x + acc[4]; o[5] = o1.y + acc[5];
            o[6] = o1.z + acc[6]; o[7] = o1.w + acc[7];
            reinterpret_cast<float4*>(op)[0] = make_float4(o[0], o[1], o[2], o[3]);
            reinterpret_cast<float4*>(op)[1] = make_float4(o[4], o[5], o[6], o[7]);
        }
    }

    if (rep) {
        const int lane = t & 63, wave = t >> 6;
        float s[8], qq[8];
#pragma unroll
        for (int k = 0; k < 8; ++k) { s[k] = o[k]; qq[k] = o[k] * o[k]; }
#pragma unroll
        for (int k = 0; k < 8; ++k) {
            s[k]  += __shfl_xor(s[k], 16);  qq[k] += __shfl_xor(qq[k], 16);
            s[k]  += __shfl_xor(s[k], 32);  qq[k] += __shfl_xor(qq[k], 32);
        }
        if (lane < 16) {
#pragma unroll
            for (int k = 0; k < 8; ++k) {
                part[wave][lane][k]     = s[k];
                part[wave][lane][8 + k] = qq[k];
            }
        }
        __syncthreads();
        int l8b = t >> 4, slot = t & 15;
        float tot = part[0][l8b][slot] + part[1][l8b][slot] +
                    part[2][l8b][slot] + part[3][l8b][slot];
        int col = l8b * 8 + (slot & 7);
        float* dst = rep + (size_t)(blockIdx.x & (NREP - 1)) * 256 +
                     (slot < 8 ? col : 128 + col);
        atomicAdd(dst, tot);
    }
}

// ---------------------------------------------------------------------------
__global__ void reduce_stats_kernel(const float* __restrict__ rep,
                                    float* __restrict__ sf) {
    int t = threadIdx.x;   // 256
    float s = 0.f;
#pragma unroll 8
    for (int r = 0; r < NREP; ++r) s += rep[r * 256 + t];
    sf[t] = s;
}

__global__ void zero_kernel(float* __restrict__ p, int n) {
    int i = blockIdx.x * 256 + threadIdx.x;
    if (i < n) p[i] = 0.f;
}

// ---------------------------------------------------------------------------
extern "C" void kernel_launch(void* const* d_in, const int* in_sizes, int n_in,
                              void* d_out, int out_size, void* d_ws, size_t ws_size,
                              hipStream_t stream) {
    const float* feat  = (const float*)d_in[0];
    const int*   edges = (const int*)d_in[1];
    const float* W0    = (const float*)d_in[2];
    const float* b0    = (const float*)d_in[3];
    const float* W1    = (const float*)d_in[4];
    const float* b1    = (const float*)d_in[5];
    const float* gamma = (const float*)d_in[6];
    const float* beta  = (const float*)d_in[7];
    float* out = (float*)d_out;

    unsigned short* hb = (unsigned short*)d_ws;   // [V,128] bf16 h0/activations
    unsigned short* yb = hb + VD;                 // [V,128] bf16 messages
    unsigned short* wp = yb + VD;                 // 8 x 16384 bf16 packed weights
    float* rep     = (float*)(wp + 8 * 16384);    // 3 x NREP x 256
    float* sf      = rep + 3 * NREP * 256;        // 3 x 256 final stats
    int*   deg     = (int*)(sf + 768);            // V
    int*   offsets = deg + V_NODES;               // V+1
    int*   cursor  = offsets + V_NODES + 1;       // V
    int*   bsums   = cursor + V_NODES;            // <=512
    int*   adj     = bsums + 512;                 // 2E

    const int V = V_NODES, E = E_EDGES;
    const int gemm_blocks = (V + 63) / 64;       // 1563
    const int gath_blocks = (V + 15) / 16;       // 6250
    const int vblocks     = (V + 255) / 256;     // 391
    const int eblocks     = (E + 255) / 256;     // 2344
    const int rep_total   = 3 * NREP * 256;      // 49152

    // Per-launch prep
    pack_w_kernel<<<dim3(64, 8), 256, 0, stream>>>(W0, W1, wp);
    zero_kernel<<<(rep_total + 255) / 256, 256, 0, stream>>>(rep, rep_total);
    zero_int_kernel<<<vblocks, 256, 0, stream>>>(deg, V);
    degree_kernel<<<eblocks, 256, 0, stream>>>(edges, deg, E);
    block_sum_kernel<<<vblocks, 256, 0, stream>>>(deg, bsums, V);
    scan_bsums_kernel<<<1, 512, 0, stream>>>(bsums, vblocks);
    offsets_kernel<<<vblocks, 256, 0, stream>>>(deg, bsums, offsets, cursor, V);
    fill_adj_kernel<<<8 * eblocks, 256, 0, stream>>>(edges, cursor, adj, E);

    for (int l = 0; l < 4; ++l) {
        const float*          xf    = (l == 0) ? feat : nullptr;
        const unsigned short* xh    = (l == 0) ? nullptr : hb;
        const float*          stats = (l == 0) ? nullptr : sf + (size_t)(l - 1) * 256;
        const float*          gam   = (l == 0) ? nullptr : gamma + (l - 1) * 128;
        const float*          bet   = (l == 0) ? nullptr : beta + (l - 1) * 128;
        const float*          res   = (l == 3) ? feat : nullptr;
        float*          outf = (l == 3) ? out : nullptr;
        unsigned short* outh = (l == 3) ? nullptr : hb;

        gemm_fused_kernel<<<gemm_blocks, 256, 0, stream>>>(
            xf, xh, stats, gam, bet, res,
            wp + (size_t)(2 * l) * 16384,     b0 + l * 128, outf, outh,
            wp + (size_t)(2 * l + 1) * 16384, b1 + l * 128, yb,
            V);

        float* rep_l = (l < 3) ? rep + (size_t)l * NREP * 256 : nullptr;
        gather_stats_kernel<<<gath_blocks, 256, 0, stream>>>(
            yb, offsets, adj, outf, outh, rep_l, V);
        if (l < 3)
            reduce_stats_kernel<<<1, 256, 0, stream>>>(rep_l, sf + (size_t)l * 256);
    }
}

// Round 7
// 579.455 us; speedup vs baseline: 15.2088x; 1.1004x over previous
//
#include <hip/hip_runtime.h>
#include <hip/hip_bf16.h>

#define V_NODES 100000
#define E_EDGES 600000
#define D_FEAT  128
#define VD      ((size_t)V_NODES * D_FEAT)
#define NREP    64
#define PART_SZ 12500   // V/8 for XCD-aligned adj partitioning
#define STRIDE  136     // LDS row stride (ushorts): 272B, 16B-aligned, bank-spread
#define SADJ_CAP 1024

typedef short bf16x8 __attribute__((ext_vector_type(8)));
typedef float f32x4  __attribute__((ext_vector_type(4)));

__device__ inline unsigned short f2bf(float f) {
    __hip_bfloat16 h = __float2bfloat16(f);
    unsigned short u;
    __builtin_memcpy(&u, &h, 2);
    return u;
}
__device__ inline float bfhi(unsigned int u) { return __uint_as_float(u & 0xffff0000u); }
__device__ inline float bflo(unsigned int u) { return __uint_as_float(u << 16); }

// ---------------------------------------------------------------------------
// Pack weights into bf16 MFMA B-fragment order (verified R4):
// wp[m][ ((s*8 + c)*64 + lane)*8 + j ] = W[c*16 + (lane&15)][s*32 + (lane>>4)*8 + j]
// ---------------------------------------------------------------------------
__global__ void pack_w_kernel(const float* __restrict__ W0,
                              const float* __restrict__ W1,
                              unsigned short* __restrict__ wp) {
    int m = blockIdx.y;            // 0..7
    int l = m >> 1, sel = m & 1;
    const float* W = (sel ? W1 : W0) + (size_t)l * 16384;
    int i = blockIdx.x * 256 + threadIdx.x;   // 0..16383
    int j    = i & 7;
    int lane = (i >> 3) & 63;
    int c    = (i >> 9) & 7;
    int s    = i >> 12;
    int n0 = lane & 15, q = lane >> 4;
    float v = W[(c * 16 + n0) * 128 + s * 32 + q * 8 + j];
    wp[(size_t)m * 16384 + i] = f2bf(v);
}

// ---------------------------------------------------------------------------
// Fused GEMM. A = relu(norm(x) [+res]) built inline as bf16 fragments.
// Outputs staged through LDS for fully-coalesced 16B stores.
// ---------------------------------------------------------------------------
__global__ __launch_bounds__(256) void gemm_fused_kernel(
    const float* __restrict__ xf, const unsigned short* __restrict__ xh,
    const float* __restrict__ stats,   // null => no BN (layer 0)
    const float* __restrict__ gamma, const float* __restrict__ beta,
    const float* __restrict__ res,     // null unless layer 3
    const unsigned short* __restrict__ wp0, const float* __restrict__ bias0,
    float* __restrict__ outf, unsigned short* __restrict__ outh,
    const unsigned short* __restrict__ wp1, const float* __restrict__ bias1,
    unsigned short* __restrict__ yb,
    int V) {
    __shared__ float lsc[128], lsh[128];
    __shared__ unsigned short st_h[64 * STRIDE];
    __shared__ unsigned short st_y[64 * STRIDE];
    const int t = threadIdx.x;
    if (stats) {
        if (t < 128) {
            float inv = 1.0f / (float)V;
            float mu  = stats[t] * inv;
            float var = stats[128 + t] * inv - mu * mu;
            float sc  = gamma[t] * rsqrtf(var + 1e-5f);
            lsc[t] = sc;
            lsh[t] = beta[t] - mu * sc;
        }
        __syncthreads();
    }

    const int wave = t >> 6;
    const int lane = t & 63;
    const int n0   = lane & 15;
    const int q    = lane >> 4;

    const int arow = blockIdx.x * 64 + wave * 16 + n0;
    bf16x8 a[4];
    {
        bf16x8 z = {0, 0, 0, 0, 0, 0, 0, 0};
#pragma unroll
        for (int s = 0; s < 4; ++s) a[s] = z;
    }
    if (arow < V) {
        const float* rr = res ? res + (size_t)arow * 128 : nullptr;
#pragma unroll
        for (int s = 0; s < 4; ++s) {
            int base = s * 32 + q * 8;
            float v[8];
            if (xh) {
                uint4 p = *reinterpret_cast<const uint4*>(xh + (size_t)arow * 128 + base);
                v[0] = bflo(p.x); v[1] = bfhi(p.x);
                v[2] = bflo(p.y); v[3] = bfhi(p.y);
                v[4] = bflo(p.z); v[5] = bfhi(p.z);
                v[6] = bflo(p.w); v[7] = bfhi(p.w);
            } else {
                const float* xr = xf + (size_t)arow * 128 + base;
                float4 p0 = *reinterpret_cast<const float4*>(xr);
                float4 p1 = *reinterpret_cast<const float4*>(xr + 4);
                v[0] = p0.x; v[1] = p0.y; v[2] = p0.z; v[3] = p0.w;
                v[4] = p1.x; v[5] = p1.y; v[6] = p1.z; v[7] = p1.w;
            }
            if (stats) {
#pragma unroll
                for (int j = 0; j < 8; ++j)
                    v[j] = v[j] * lsc[base + j] + lsh[base + j];
                if (rr) {
                    float4 r0 = *reinterpret_cast<const float4*>(rr + base);
                    float4 r1 = *reinterpret_cast<const float4*>(rr + base + 4);
                    v[0] += r0.x; v[1] += r0.y; v[2] += r0.z; v[3] += r0.w;
                    v[4] += r1.x; v[5] += r1.y; v[6] += r1.z; v[7] += r1.w;
                }
#pragma unroll
                for (int j = 0; j < 8; ++j) v[j] = fmaxf(v[j], 0.f);
            }
            bf16x8 af;
#pragma unroll
            for (int j = 0; j < 8; ++j) af[j] = (short)f2bf(v[j]);
            a[s] = af;
        }
    }

    f32x4 acc0[8], acc1[8];
    f32x4 z4 = {0.f, 0.f, 0.f, 0.f};
#pragma unroll
    for (int c = 0; c < 8; ++c) { acc0[c] = z4; acc1[c] = z4; }

#pragma unroll
    for (int c = 0; c < 8; ++c) {
#pragma unroll
        for (int s = 0; s < 4; ++s) {
            size_t off = ((size_t)((s * 8 + c) * 64 + lane)) * 8;
            bf16x8 b0f = *reinterpret_cast<const bf16x8*>(wp0 + off);
            bf16x8 b1f = *reinterpret_cast<const bf16x8*>(wp1 + off);
            acc0[c] = __builtin_amdgcn_mfma_f32_16x16x32_bf16(a[s], b0f, acc0[c], 0, 0, 0);
            acc1[c] = __builtin_amdgcn_mfma_f32_16x16x32_bf16(a[s], b1f, acc1[c], 0, 0, 0);
        }
    }

    // Stage outputs in LDS. C/D layout: col = lane&15 (n0), row = q*4 + reg.
    const int lrow0 = wave * 16 + q * 4;
#pragma unroll
    for (int c = 0; c < 8; ++c) {
        float bv0 = bias0[c * 16 + n0];
        float bv1 = bias1[c * 16 + n0];
#pragma unroll
        for (int r = 0; r < 4; ++r) {
            int a_ = (lrow0 + r) * STRIDE + c * 16 + n0;
            st_h[a_] = f2bf(acc0[c][r] + bv0);
            st_y[a_] = f2bf(acc1[c][r] + bv1);
        }
    }
    // Also serves as the barrier protecting in-place xsrc==outh row overwrite.
    __syncthreads();

    // Coalesced write-back: 1024 chunks of 8 ushorts (16B).
#pragma unroll
    for (int it = 0; it < 4; ++it) {
        int chunk = it * 256 + t;
        int lrow = chunk >> 4, c8 = chunk & 15;
        int grow = blockIdx.x * 64 + lrow;
        if (grow < V) {
            size_t gidx = (size_t)grow * 128 + c8 * 8;
            uint4 hy = *reinterpret_cast<const uint4*>(&st_y[lrow * STRIDE + c8 * 8]);
            *reinterpret_cast<uint4*>(&yb[gidx]) = hy;
            uint4 hh = *reinterpret_cast<const uint4*>(&st_h[lrow * STRIDE + c8 * 8]);
            if (outh) {
                *reinterpret_cast<uint4*>(&outh[gidx]) = hh;
            } else {
                float4 f0 = make_float4(bflo(hh.x), bfhi(hh.x), bflo(hh.y), bfhi(hh.y));
                float4 f1 = make_float4(bflo(hh.z), bfhi(hh.z), bflo(hh.w), bfhi(hh.w));
                *reinterpret_cast<float4*>(&outf[gidx])     = f0;
                *reinterpret_cast<float4*>(&outf[gidx + 4]) = f1;
            }
        }
    }
}

// ---------------------------------------------------------------------------
// CSR construction — multi-block scan
// ---------------------------------------------------------------------------
__global__ void zero_int_kernel(int* __restrict__ p, int n) {
    int i = blockIdx.x * 256 + threadIdx.x;
    if (i < n) p[i] = 0;
}

__global__ __launch_bounds__(256) void degree_kernel(
    const int* __restrict__ edges, int* __restrict__ deg, int E) {
    int i = blockIdx.x * 256 + threadIdx.x;
    if (i >= E) return;
    atomicAdd(&deg[edges[2 * i]], 1);
    atomicAdd(&deg[edges[2 * i + 1]], 1);
}

__global__ __launch_bounds__(256) void block_sum_kernel(
    const int* __restrict__ deg, int* __restrict__ bsums, int V) {
    __shared__ int sh[256];
    int i = blockIdx.x * 256 + threadIdx.x;
    sh[threadIdx.x] = (i < V) ? deg[i] : 0;
    __syncthreads();
    for (int off = 128; off > 0; off >>= 1) {
        if (threadIdx.x < off) sh[threadIdx.x] += sh[threadIdx.x + off];
        __syncthreads();
    }
    if (threadIdx.x == 0) bsums[blockIdx.x] = sh[0];
}

__global__ __launch_bounds__(512) void scan_bsums_kernel(int* __restrict__ bsums, int nb) {
    __shared__ int sh[512];
    int t = threadIdx.x;
    int v = (t < nb) ? bsums[t] : 0;
    sh[t] = v;
    __syncthreads();
    for (int off = 1; off < 512; off <<= 1) {
        int add = (t >= off) ? sh[t - off] : 0;
        __syncthreads();
        sh[t] += add;
        __syncthreads();
    }
    if (t < nb) bsums[t] = sh[t] - v;   // exclusive
}

__global__ __launch_bounds__(256) void offsets_kernel(
    const int* __restrict__ deg, const int* __restrict__ bsums,
    int* __restrict__ offsets, int* __restrict__ cursor, int V) {
    __shared__ int sh[256];
    int t = threadIdx.x;
    int i = blockIdx.x * 256 + t;
    int v = (i < V) ? deg[i] : 0;
    sh[t] = v;
    __syncthreads();
    for (int off = 1; off < 256; off <<= 1) {
        int add = (t >= off) ? sh[t - off] : 0;
        __syncthreads();
        sh[t] += add;
        __syncthreads();
    }
    int excl = sh[t] - v + bsums[blockIdx.x];
    if (i < V) { offsets[i] = excl; cursor[i] = excl; }
    if (i == V - 1) offsets[V] = excl + v;
}

// XCD-partitioned adj fill (verified R6: kills partial-line writeback storm).
__global__ __launch_bounds__(256) void fill_adj_kernel(
    const int* __restrict__ edges, int* __restrict__ cursor,
    int* __restrict__ adj, int E) {
    int part = blockIdx.x & 7;
    int i = (blockIdx.x >> 3) * 256 + threadIdx.x;
    if (i >= E) return;
    int a = edges[2 * i], b = edges[2 * i + 1];
    if (a / PART_SZ == part) { int pa = atomicAdd(&cursor[a], 1); adj[pa] = b; }
    if (b / PART_SZ == part) { int pb = atomicAdd(&cursor[b], 1); adj[pb] = a; }
}

// ---------------------------------------------------------------------------
// Gather + fused BN stats. 16 lanes/node (8 bf16 cols/lane).
// Block's 16-node CSR segment prefetched into LDS.
// ---------------------------------------------------------------------------
__global__ __launch_bounds__(256) void gather_stats_kernel(
    const unsigned short* __restrict__ yb, const int* __restrict__ offsets,
    const int* __restrict__ adj,
    float* __restrict__ outf, unsigned short* __restrict__ outh,
    float* __restrict__ rep, int V) {
    __shared__ int sadj[SADJ_CAP];
    __shared__ float part[4][16][16];
    const int t    = threadIdx.x;
    const int nodeBase = blockIdx.x * 16;
    const int node = nodeBase + (t >> 4);
    const int l8   = t & 15;                 // cols l8*8 .. +7

    const int segStart = offsets[min(nodeBase, V)];
    const int segEnd   = offsets[min(nodeBase + 16, V)];
    const int segLen   = segEnd - segStart;
    const bool inLds   = (segLen <= SADJ_CAP);
    if (inLds)
        for (int j = t; j < segLen; j += 256) sadj[j] = adj[segStart + j];
    __syncthreads();

    float o[8];
#pragma unroll
    for (int k = 0; k < 8; ++k) o[k] = 0.f;

    if (node < V) {
        int start = offsets[node] - segStart, end = offsets[node + 1] - segStart;
        float acc[8];
#pragma unroll
        for (int k = 0; k < 8; ++k) acc[k] = 0.f;

        const int* src = inLds ? sadj : adj + segStart;
        int i = start;
        for (; i + 1 < end; i += 2) {
            int u0 = src[i], u1 = src[i + 1];
            uint4 p0 = *reinterpret_cast<const uint4*>(yb + (size_t)u0 * 128 + l8 * 8);
            uint4 p1 = *reinterpret_cast<const uint4*>(yb + (size_t)u1 * 128 + l8 * 8);
            acc[0] += bflo(p0.x); acc[1] += bfhi(p0.x);
            acc[2] += bflo(p0.y); acc[3] += bfhi(p0.y);
            acc[4] += bflo(p0.z); acc[5] += bfhi(p0.z);
            acc[6] += bflo(p0.w); acc[7] += bfhi(p0.w);
            acc[0] += bflo(p1.x); acc[1] += bfhi(p1.x);
            acc[2] += bflo(p1.y); acc[3] += bfhi(p1.y);
            acc[4] += bflo(p1.z); acc[5] += bfhi(p1.z);
            acc[6] += bflo(p1.w); acc[7] += bfhi(p1.w);
        }
        if (i < end) {
            int u0 = src[i];
            uint4 p0 = *reinterpret_cast<const uint4*>(yb + (size_t)u0 * 128 + l8 * 8);
            acc[0] += bflo(p0.x); acc[1] += bfhi(p0.x);
            acc[2] += bflo(p0.y); acc[3] += bfhi(p0.y);
            acc[4] += bflo(p0.z); acc[5] += bfhi(p0.z);
            acc[6] += bflo(p0.w); acc[7] += bfhi(p0.w);
        }

        if (outh) {
            unsigned short* op = outh + (size_t)node * 128 + l8 * 8;
            uint4 h = *reinterpret_cast<const uint4*>(op);
            o[0] = bflo(h.x) + acc[0]; o[1] = bfhi(h.x) + acc[1];
            o[2] = bflo(h.y) + acc[2]; o[3] = bfhi(h.y) + acc[3];
            o[4] = bflo(h.z) + acc[4]; o[5] = bfhi(h.z) + acc[5];
            o[6] = bflo(h.w) + acc[6]; o[7] = bfhi(h.w) + acc[7];
            uint4 hn;
            hn.x = (unsigned)f2bf(o[0]) | ((unsigned)f2bf(o[1]) << 16);
            hn.y = (unsigned)f2bf(o[2]) | ((unsigned)f2bf(o[3]) << 16);
            hn.z = (unsigned)f2bf(o[4]) | ((unsigned)f2bf(o[5]) << 16);
            hn.w = (unsigned)f2bf(o[6]) | ((unsigned)f2bf(o[7]) << 16);
            *reinterpret_cast<uint4*>(op) = hn;
        } else {
            float* op = outf + (size_t)node * 128 + l8 * 8;
            float4 o0 = reinterpret_cast<const float4*>(op)[0];
            float4 o1 = reinterpret_cast<const float4*>(op)[1];
            o[0] = o0.x + acc[0]; o[1] = o0.y + acc[1];
            o[2] = o0.z + acc[2]; o[3] = o0.w + acc[3];
            o[4] = o1.x + acc[4]; o[5] = o1.y + acc[5];
            o[6] = o1.z + acc[6]; o[7] = o1.w + acc[7];
            reinterpret_cast<float4*>(op)[0] = make_float4(o[0], o[1], o[2], o[3]);
            reinterpret_cast<float4*>(op)[1] = make_float4(o[4], o[5], o[6], o[7]);
        }
    }

    if (rep) {
        const int lane = t & 63, wave = t >> 6;
        float s[8], qq[8];
#pragma unroll
        for (int k = 0; k < 8; ++k) { s[k] = o[k]; qq[k] = o[k] * o[k]; }
#pragma unroll
        for (int k = 0; k < 8; ++k) {
            s[k]  += __shfl_xor(s[k], 16);  qq[k] += __shfl_xor(qq[k], 16);
            s[k]  += __shfl_xor(s[k], 32);  qq[k] += __shfl_xor(qq[k], 32);
        }
        if (lane < 16) {
#pragma unroll
            for (int k = 0; k < 8; ++k) {
                part[wave][lane][k]     = s[k];
                part[wave][lane][8 + k] = qq[k];
            }
        }
        __syncthreads();
        int l8b = t >> 4, slot = t & 15;
        float tot = part[0][l8b][slot] + part[1][l8b][slot] +
                    part[2][l8b][slot] + part[3][l8b][slot];
        int col = l8b * 8 + (slot & 7);
        float* dst = rep + (size_t)(blockIdx.x & (NREP - 1)) * 256 +
                     (slot < 8 ? col : 128 + col);
        atomicAdd(dst, tot);
    }
}

// ---------------------------------------------------------------------------
__global__ void reduce_stats_kernel(const float* __restrict__ rep,
                                    float* __restrict__ sf) {
    int t = threadIdx.x;   // 256
    float s = 0.f;
#pragma unroll 8
    for (int r = 0; r < NREP; ++r) s += rep[r * 256 + t];
    sf[t] = s;
}

__global__ void zero_kernel(float* __restrict__ p, int n) {
    int i = blockIdx.x * 256 + threadIdx.x;
    if (i < n) p[i] = 0.f;
}

// ---------------------------------------------------------------------------
extern "C" void kernel_launch(void* const* d_in, const int* in_sizes, int n_in,
                              void* d_out, int out_size, void* d_ws, size_t ws_size,
                              hipStream_t stream) {
    const float* feat  = (const float*)d_in[0];
    const int*   edges = (const int*)d_in[1];
    const float* W0    = (const float*)d_in[2];
    const float* b0    = (const float*)d_in[3];
    const float* W1    = (const float*)d_in[4];
    const float* b1    = (const float*)d_in[5];
    const float* gamma = (const float*)d_in[6];
    const float* beta  = (const float*)d_in[7];
    float* out = (float*)d_out;

    unsigned short* hb = (unsigned short*)d_ws;   // [V,128] bf16 h0/activations
    unsigned short* yb = hb + VD;                 // [V,128] bf16 messages
    unsigned short* wp = yb + VD;                 // 8 x 16384 bf16 packed weights
    float* rep     = (float*)(wp + 8 * 16384);    // 3 x NREP x 256
    float* sf      = rep + 3 * NREP * 256;        // 3 x 256 final stats
    int*   deg     = (int*)(sf + 768);            // V
    int*   offsets = deg + V_NODES;               // V+1
    int*   cursor  = offsets + V_NODES + 1;       // V
    int*   bsums   = cursor + V_NODES;            // <=512
    int*   adj     = bsums + 512;                 // 2E

    const int V = V_NODES, E = E_EDGES;
    const int gemm_blocks = (V + 63) / 64;       // 1563
    const int gath_blocks = (V + 15) / 16;       // 6250
    const int vblocks     = (V + 255) / 256;     // 391
    const int eblocks     = (E + 255) / 256;     // 2344
    const int rep_total   = 3 * NREP * 256;      // 49152

    // Per-launch prep
    pack_w_kernel<<<dim3(64, 8), 256, 0, stream>>>(W0, W1, wp);
    zero_kernel<<<(rep_total + 255) / 256, 256, 0, stream>>>(rep, rep_total);
    zero_int_kernel<<<vblocks, 256, 0, stream>>>(deg, V);
    degree_kernel<<<eblocks, 256, 0, stream>>>(edges, deg, E);
    block_sum_kernel<<<vblocks, 256, 0, stream>>>(deg, bsums, V);
    scan_bsums_kernel<<<1, 512, 0, stream>>>(bsums, vblocks);
    offsets_kernel<<<vblocks, 256, 0, stream>>>(deg, bsums, offsets, cursor, V);
    fill_adj_kernel<<<8 * eblocks, 256, 0, stream>>>(edges, cursor, adj, E);

    for (int l = 0; l < 4; ++l) {
        const float*          xf    = (l == 0) ? feat : nullptr;
        const unsigned short* xh    = (l == 0) ? nullptr : hb;
        const float*          stats = (l == 0) ? nullptr : sf + (size_t)(l - 1) * 256;
        const float*          gam   = (l == 0) ? nullptr : gamma + (l - 1) * 128;
        const float*          bet   = (l == 0) ? nullptr : beta + (l - 1) * 128;
        const float*          res   = (l == 3) ? feat : nullptr;
        float*          outf = (l == 3) ? out : nullptr;
        unsigned short* outh = (l == 3) ? nullptr : hb;

        gemm_fused_kernel<<<gemm_blocks, 256, 0, stream>>>(
            xf, xh, stats, gam, bet, res,
            wp + (size_t)(2 * l) * 16384,     b0 + l * 128, outf, outh,
            wp + (size_t)(2 * l + 1) * 16384, b1 + l * 128, yb,
            V);

        float* rep_l = (l < 3) ? rep + (size_t)l * NREP * 256 : nullptr;
        gather_stats_kernel<<<gath_blocks, 256, 0, stream>>>(
            yb, offsets, adj, outf, outh, rep_l, V);
        if (l < 3)
            reduce_stats_kernel<<<1, 256, 0, stream>>>(rep_l, sf + (size_t)l * 256);
    }
}